// Round 4
// baseline (393.351 us; speedup 1.0000x reference)
//
#include <hip/hip_runtime.h>
#include <hip/hip_cooperative_groups.h>
#include <math.h>

namespace cg = cooperative_groups;

#define Bb   256
#define Lq   128
#define D1   768
#define Hh   1024
#define Kk   256
#define K2v  512

// ---- ws float offsets ----
#define OFF_EPSG  0                    // 512*256
#define OFF_P     131072               // 2097152 floats (partial arena)
#define OFF_Z     2228224              // 512*256
#define OFF_SCORE 2359296              // 512*256
#define OFF_DIST  2490368              // 65536
#define OFF_HIST  2555904              // 8192 ints
#define OFF_SCAL  2564096              // [0]=kl_i [1]=kl_t [2]=align
#define OFF_YSY   2564104              // 512
#define OFF_SEQL  2564616              // 256 ints
#define OFF_BF    2564880              // ushort arena (16B aligned)

// ---- ushort offsets inside bf arena ----
#define UB_XG   0                      // 512*768
#define UB_HACT 393216                 // 512*1024 (reused 512*512)
#define UB_ZB   917504                 // 512*256
#define UB_WT   1048576                // transposed bf16 weights
#define WT_EW1I 0
#define WT_EW1T 786432
#define WT_EW2I 1572864
#define WT_EW2T 2097152
#define WT_SW1I 2621440
#define WT_SW1T 2752512
#define WT_SW2I 2883584
#define WT_SW2T 3014656

typedef __attribute__((ext_vector_type(8))) short short8v;
typedef __attribute__((ext_vector_type(4))) float f32x4;

__device__ __forceinline__ float wred(float v){
#pragma unroll
  for (int m = 32; m; m >>= 1) v += __shfl_xor(v, m, 64);
  return v;
}
__device__ __forceinline__ int wredi(int v){
#pragma unroll
  for (int m = 32; m; m >>= 1) v += __shfl_xor(v, m, 64);
  return v;
}
__device__ __forceinline__ float gelu_exact(float x){
  return 0.5f * x * (1.0f + erff(x * 0.70710678118654752f));
}
__device__ __forceinline__ ushort f2b(float f){
  union { float f; unsigned u; } v; v.f = f;
  return (ushort)((v.u + 0x7FFFu + ((v.u >> 16) & 1u)) >> 16);
}

struct Params {
  const float *img, *txt, *epsi, *epst;
  const int   *mask;
  const float *eW1i,*eb1i,*egi,*ebei,*eW2i,*eb2i;
  const float *eW1t,*eb1t,*egt,*ebet,*eW2t,*eb2t;
  const float *sW1i,*sb1i,*sgi,*sbei,*sW2i,*sb2i;
  const float *sW1t,*sb1t,*sgt,*sbet,*sW2t,*sb2t;
  float *ws;
  float *out;
};

// shared-memory overlays
struct ConvSM  { float lsf[32][33]; };
struct DistSM  { float xsh[256]; int hl[8192]; };
struct ScoreSM { float xsh[256]; float sxsh[256]; int wt4[4]; int bres[2]; float red4[4]; float bw2; };
struct LNSM    { float2 wsum[4]; };

// ---- MFMA bf16 GEMM stage (K-split partials into P) ----
template<int BM,int KCH,int N,int K>
__device__ __forceinline__ void gemm_stage(
    const ushort* __restrict__ A, const ushort* __restrict__ WTi,
    const ushort* __restrict__ WTt, float* __restrict__ P,
    ushort* LS, int tid, int n0, int r0, int kb, int ks)
{
  constexpr int RPW = BM / 64;
  const int lane = tid & 63, wid = tid >> 6;
  const ushort* WT = (r0 >= 256) ? WTt : WTi;

  f32x4 acc[RPW][4];
#pragma unroll
  for (int s = 0; s < RPW; s++)
#pragma unroll
    for (int c = 0; c < 4; c++) acc[s][c] = (f32x4){0.f,0.f,0.f,0.f};

  const int l15 = lane & 15, kg = lane >> 4;
  const int rdswz = (kg * 16) ^ ((l15 & 3) << 4);

  for (int k0 = kb; k0 < kb + KCH; k0 += 32){
    __syncthreads();
    constexpr int NCHK = (BM + 64) * 4;
#pragma unroll
    for (int i = 0; i < NCHK / 256; i++){
      const int q = (i * 256 + tid) * 16;
      const int row = q >> 6, koff = q & 63;
      const ushort* src = (row < BM)
          ? (A  + (size_t)(r0 + row) * K + k0)
          : (WT + (size_t)(n0 + row - BM) * K + k0);
      short8v v = *reinterpret_cast<const short8v*>(
          reinterpret_cast<const char*>(src) + koff);
      const int dq = (q & ~63) | (koff ^ ((row & 3) << 4));
      *reinterpret_cast<short8v*>(reinterpret_cast<char*>(LS) + dq) = v;
    }
    __syncthreads();
    const char* Ab  = reinterpret_cast<const char*>(LS);
    const char* Bbp = reinterpret_cast<const char*>(LS + BM * 32);
    short8v ar[RPW], bc[4];
#pragma unroll
    for (int s = 0; s < RPW; s++){
      const int row = wid * (RPW * 16) + s * 16 + l15;
      ar[s] = *reinterpret_cast<const short8v*>(Ab + row * 64 + rdswz);
    }
#pragma unroll
    for (int c = 0; c < 4; c++){
      const int col = c * 16 + l15;
      bc[c] = *reinterpret_cast<const short8v*>(Bbp + col * 64 + rdswz);
    }
#pragma unroll
    for (int s = 0; s < RPW; s++)
#pragma unroll
      for (int c = 0; c < 4; c++)
        acc[s][c] = __builtin_amdgcn_mfma_f32_16x16x32_bf16(ar[s], bc[c], acc[s][c], 0, 0, 0);
  }
#pragma unroll
  for (int s = 0; s < RPW; s++)
#pragma unroll
    for (int c = 0; c < 4; c++)
#pragma unroll
      for (int r = 0; r < 4; r++){
        const int row = r0 + wid * (RPW * 16) + s * 16 + kg * 4 + r;
        const int col = n0 + c * 16 + l15;
        P[((size_t)ks * 512 + row) * N + col] = acc[s][c][r];
      }
}

// ---- LN+gelu over W-wide row, summing NS partials + bias -> bf16 ----
template<int W, int NS>
__device__ __forceinline__ void ln_row(
    const float* __restrict__ P, int row,
    const float* __restrict__ b1, const float* __restrict__ g,
    const float* __restrict__ be, ushort* __restrict__ hb,
    LNSM* sm, int t)
{
  // W/4 float4 per row; threads t < W/4 active
  float4 v = make_float4(0,0,0,0);
  if (t < W/4){
    const float4* P4 = reinterpret_cast<const float4*>(P);
#pragma unroll
    for (int s = 0; s < NS; s++){
      float4 p = P4[((size_t)s * 512 + row) * (W/4) + t];
      v.x += p.x; v.y += p.y; v.z += p.z; v.w += p.w;
    }
    float4 bb = reinterpret_cast<const float4*>(b1)[t];
    v.x += bb.x; v.y += bb.y; v.z += bb.z; v.w += bb.w;
  }
  float ps = wred(v.x + v.y + v.z + v.w);
  float pq = wred(v.x*v.x + v.y*v.y + v.z*v.z + v.w*v.w);
  if (!(t & 63)) sm->wsum[t >> 6] = make_float2(ps, pq);
  __syncthreads();
  float S = 0, Q = 0;
#pragma unroll
  for (int i = 0; i < (W == 1024 ? 4 : 2); i++){ S += sm->wsum[i].x; Q += sm->wsum[i].y; }
  if (t < W/4){
    float mean = S * (1.0f/W);
    float rstd = rsqrtf(Q * (1.0f/W) - mean*mean + 1e-5f);
    float4 gv  = reinterpret_cast<const float4*>(g)[t];
    float4 bev = reinterpret_cast<const float4*>(be)[t];
    ushort4 o;
    o.x = f2b(gelu_exact((v.x - mean)*rstd*gv.x + bev.x));
    o.y = f2b(gelu_exact((v.y - mean)*rstd*gv.y + bev.y));
    o.z = f2b(gelu_exact((v.z - mean)*rstd*gv.z + bev.z));
    o.w = f2b(gelu_exact((v.w - mean)*rstd*gv.w + bev.w));
    reinterpret_cast<ushort4*>(hb)[(size_t)row * (W/4) + t] = o;
  }
}

__global__ __launch_bounds__(256) void k_mega(Params p)
{
  __shared__ __align__(16) char SMRAW[sizeof(DistSM)];
  __shared__ int s_last;
  cg::grid_group grid = cg::this_grid();

  const int bid = blockIdx.x;          // 0..255
  const int t   = threadIdx.x;         // 0..255

  float*  ws    = p.ws;
  float*  epsg  = ws + OFF_EPSG;
  float*  P     = ws + OFF_P;
  float*  z     = ws + OFF_Z;
  float*  score = ws + OFF_SCORE;
  float*  dist  = ws + OFF_DIST;
  int*    ghist = (int*)(ws + OFF_HIST);
  float*  scal  = ws + OFF_SCAL;
  float*  ysy   = ws + OFF_YSY;
  int*    seql  = (int*)(ws + OFF_SEQL);
  ushort* ub    = (ushort*)(ws + OFF_BF);
  ushort* xgb   = ub + UB_XG;
  ushort* hb    = ub + UB_HACT;
  ushort* zb    = ub + UB_ZB;
  ushort* wt    = ub + UB_WT;

  // ================= stage 1: prep (seql, zero, gather) + weight conv =================
  {
    // seq_last for row bid
    int s = 0;
    if (t < 32){
      int4 v = reinterpret_cast<const int4*>(p.mask + bid * Lq)[t];
      s = v.x + v.y + v.z + v.w;
    }
    if (t < 64){
      int tot = wredi(s);
      if (t == 0){ seql[bid] = tot - 1; s_last = tot - 1; }
    }
    // zero hist / scal
    if (t < 8) reinterpret_cast<int4*>(ghist)[bid * 8 + t] = make_int4(0,0,0,0);
    if (bid == 0 && t < 8) scal[t] = 0.0f;
    __syncthreads();
    const int last = s_last;
    // gather + convert x rows
    if (t < 192){
      float4 v = reinterpret_cast<const float4*>(p.img + (size_t)(bid*Lq+last)*D1)[t];
      ushort4 o; o.x=f2b(v.x); o.y=f2b(v.y); o.z=f2b(v.z); o.w=f2b(v.w);
      reinterpret_cast<ushort4*>(xgb + (size_t)bid*D1)[t] = o;
      float4 w = reinterpret_cast<const float4*>(p.txt + (size_t)(bid*Lq+last)*D1)[t];
      ushort4 q; q.x=f2b(w.x); q.y=f2b(w.y); q.z=f2b(w.z); q.w=f2b(w.w);
      reinterpret_cast<ushort4*>(xgb + (size_t)(Bb+bid)*D1)[t] = q;
    }
    if (t < 64){
      reinterpret_cast<float4*>(epsg + (size_t)bid*Kk)[t] =
        reinterpret_cast<const float4*>(p.epsi + (size_t)(bid*Lq+last)*Kk)[t];
      reinterpret_cast<float4*>(epsg + (size_t)(Bb+bid)*Kk)[t] =
        reinterpret_cast<const float4*>(p.epst + (size_t)(bid*Lq+last)*Kk)[t];
    }
    // weight transpose-convert: 3072 tiles, 12 per block
    ConvSM* cs = reinterpret_cast<ConvSM*>(SMRAW);
    for (int it = 0; it < 12; ++it){
      const int wb = bid + it * 256;
      const float* src; ushort* dst; int Kd, Nd, ti;
      if      (wb < 768){  src=p.eW1i; dst=wt+WT_EW1I; Kd=768;  Nd=1024; ti=wb; }
      else if (wb < 1536){ src=p.eW1t; dst=wt+WT_EW1T; Kd=768;  Nd=1024; ti=wb-768; }
      else if (wb < 2048){ src=p.eW2i; dst=wt+WT_EW2I; Kd=1024; Nd=512;  ti=wb-1536; }
      else if (wb < 2560){ src=p.eW2t; dst=wt+WT_EW2T; Kd=1024; Nd=512;  ti=wb-2048; }
      else if (wb < 2688){ src=p.sW1i; dst=wt+WT_SW1I; Kd=256;  Nd=512;  ti=wb-2560; }
      else if (wb < 2816){ src=p.sW1t; dst=wt+WT_SW1T; Kd=256;  Nd=512;  ti=wb-2688; }
      else if (wb < 2944){ src=p.sW2i; dst=wt+WT_SW2I; Kd=512;  Nd=256;  ti=wb-2816; }
      else               { src=p.sW2t; dst=wt+WT_SW2T; Kd=512;  Nd=256;  ti=wb-2944; }
      const int ntile = Nd / 32;
      const int k0 = (ti / ntile) * 32, n0 = (ti % ntile) * 32;
      const int r = t >> 3, q = t & 7;
      float4 v = reinterpret_cast<const float4*>(src + (size_t)(k0+r)*Nd + n0)[q];
      __syncthreads();
      cs->lsf[r][q*4+0]=v.x; cs->lsf[r][q*4+1]=v.y; cs->lsf[r][q*4+2]=v.z; cs->lsf[r][q*4+3]=v.w;
      __syncthreads();
      ushort4 o;
      o.x = f2b(cs->lsf[q*4+0][r]); o.y = f2b(cs->lsf[q*4+1][r]);
      o.z = f2b(cs->lsf[q*4+2][r]); o.w = f2b(cs->lsf[q*4+3][r]);
      *reinterpret_cast<ushort4*>(dst + (size_t)(n0+r)*Kd + k0 + q*4) = o;
    }
  }
  grid.sync();

  // ================= stage 2: enc GEMM1 [512,768]@[768,1024], ks=4 =================
  {
    ushort* LS = reinterpret_cast<ushort*>(SMRAW);
    const int n0 = (bid & 15) * 64, m = (bid >> 4) & 3, ks = bid >> 6;
    gemm_stage<128,192,1024,768>(xgb, wt+WT_EW1I, wt+WT_EW1T, P, LS, t, n0, m*128, ks*192, ks);
  }
  grid.sync();

  // ================= stage 3: LN1 (1024-wide, 4 partials) =================
  {
    LNSM* sm = reinterpret_cast<LNSM*>(SMRAW);
#pragma unroll
    for (int rr = 0; rr < 2; rr++){
      const int row = bid + rr * 256;
      __syncthreads();
      ln_row<1024,4>(P, row, row >= 256 ? p.eb1t : p.eb1i,
                     row >= 256 ? p.egt : p.egi,
                     row >= 256 ? p.ebet : p.ebei, hb, sm, t);
    }
  }
  grid.sync();

  // ================= stage 4: enc GEMM2 [512,1024]@[1024,512], ks=8 =================
  {
    ushort* LS = reinterpret_cast<ushort*>(SMRAW);
    const int n0 = (bid & 7) * 64, m = (bid >> 3) & 3, ks = bid >> 5;
    gemm_stage<128,128,512,1024>(hb, wt+WT_EW2I, wt+WT_EW2T, P, LS, t, n0, m*128, ks*128, ks);
  }
  grid.sync();

  // ================= stage 5: reparam + normalize + KL (8 partials) =================
  {
    const int wv = t >> 6, lane = t & 63;
    if (wv < 2 && lane < 64){
      const int row = bid + wv * 256;
      const float* b2 = row >= 256 ? p.eb2t : p.eb2i;
      const float4* P4 = reinterpret_cast<const float4*>(P);
      float4 mu = make_float4(0,0,0,0), lv = make_float4(0,0,0,0);
#pragma unroll
      for (int s = 0; s < 8; s++){
        float4 a = P4[((size_t)s * 512 + row) * (K2v/4) + lane];
        float4 c = P4[((size_t)s * 512 + row) * (K2v/4) + 64 + lane];
        mu.x += a.x; mu.y += a.y; mu.z += a.z; mu.w += a.w;
        lv.x += c.x; lv.y += c.y; lv.z += c.z; lv.w += c.w;
      }
      float4 bm = reinterpret_cast<const float4*>(b2)[lane];
      float4 bl = reinterpret_cast<const float4*>(b2)[64 + lane];
      mu.x += bm.x; mu.y += bm.y; mu.z += bm.z; mu.w += bm.w;
      lv.x += bl.x; lv.y += bl.y; lv.z += bl.z; lv.w += bl.w;
      float4 ev = reinterpret_cast<const float4*>(epsg)[(size_t)row * 64 + lane];
      float z0 = mu.x + ev.x * expf(0.5f * lv.x);
      float z1 = mu.y + ev.y * expf(0.5f * lv.y);
      float z2 = mu.z + ev.z * expf(0.5f * lv.z);
      float z3 = mu.w + ev.w * expf(0.5f * lv.w);
      float s2 = wred(z0*z0 + z1*z1 + z2*z2 + z3*z3);
      float klp = (1.0f + lv.x - mu.x*mu.x - expf(lv.x))
                + (1.0f + lv.y - mu.y*mu.y - expf(lv.y))
                + (1.0f + lv.z - mu.z*mu.z - expf(lv.z))
                + (1.0f + lv.w - mu.w*mu.w - expf(lv.w));
      float klt = wred(klp);
      float inv = 1.0f / fmaxf(sqrtf(s2), 1e-12f);
      float4 zv = make_float4(z0*inv, z1*inv, z2*inv, z3*inv);
      reinterpret_cast<float4*>(z)[(size_t)row * 64 + lane] = zv;
      ushort4 o; o.x=f2b(zv.x); o.y=f2b(zv.y); o.z=f2b(zv.z); o.w=f2b(zv.w);
      reinterpret_cast<ushort4*>(zb)[(size_t)row * 64 + lane] = o;
      if (lane == 0) atomicAdd(scal + (row >= 256 ? 1 : 0), -0.5f * klt);
    }
  }
  grid.sync();

  // ================= stage 6: sc GEMM1 [512,256]@[256,512], ks=4 =================
  {
    ushort* LS = reinterpret_cast<ushort*>(SMRAW);
    const int n0 = (bid & 7) * 64, m = (bid >> 3) & 7, ks = bid >> 6;
    gemm_stage<64,64,512,256>(zb, wt+WT_SW1I, wt+WT_SW1T, P, LS, t, n0, m*64, ks*64, ks);
  }
  grid.sync();

  // ================= stage 7: LN2 (512-wide, 4 partials) =================
  {
    LNSM* sm = reinterpret_cast<LNSM*>(SMRAW);
#pragma unroll
    for (int rr = 0; rr < 2; rr++){
      const int row = bid + rr * 256;
      __syncthreads();
      ln_row<512,4>(P, row, row >= 256 ? p.sb1t : p.sb1i,
                    row >= 256 ? p.sgt : p.sgi,
                    row >= 256 ? p.sbet : p.sbei, hb, sm, t);
    }
  }
  grid.sync();

  // ================= stage 8: sc GEMM2 [512,512]@[512,256], ks=8 =================
  {
    ushort* LS = reinterpret_cast<ushort*>(SMRAW);
    const int n0 = (bid & 3) * 64, m = (bid >> 2) & 7, ks = bid >> 5;
    gemm_stage<64,64,256,512>(hb, wt+WT_SW2I, wt+WT_SW2T, P, LS, t, n0, m*64, ks*64, ks);
  }
  grid.sync();

  // ================= stage 9: score partial-sum (8) + bias; ysy =================
  {
    const int wv = t >> 6, lane = t & 63;
    if (wv < 2){
      const int row = bid + wv * 256;
      const float* b2 = row >= 256 ? p.sb2t : p.sb2i;
      const float4* P4 = reinterpret_cast<const float4*>(P);
      float4 v = make_float4(0,0,0,0);
#pragma unroll
      for (int s = 0; s < 8; s++){
        float4 q = P4[((size_t)s * 512 + row) * (Kk/4) + lane];
        v.x += q.x; v.y += q.y; v.z += q.z; v.w += q.w;
      }
      float4 bb = reinterpret_cast<const float4*>(b2)[lane];
      v.x += bb.x; v.y += bb.y; v.z += bb.z; v.w += bb.w;
      reinterpret_cast<float4*>(score)[(size_t)row * 64 + lane] = v;
      float4 zv = reinterpret_cast<const float4*>(z)[(size_t)row * 64 + lane];
      float yp = wred(zv.x*v.x + zv.y*v.y + zv.z*v.z + zv.w*v.w);
      if (lane == 0) ysy[row] = yp;
    }
  }
  grid.sync();

  // ================= stage 10: pairwise dist + histogram =================
  {
    DistSM* sm = reinterpret_cast<DistSM*>(SMRAW);
    const int i = bid, j = t;
    sm->xsh[j] = z[(size_t)i * Kk + j];
#pragma unroll
    for (int k = j; k < 8192; k += 256) sm->hl[k] = 0;
    __syncthreads();
    const float4* y4 = reinterpret_cast<const float4*>(z + (size_t)Bb * Kk);
    const float4* x4 = reinterpret_cast<const float4*>(sm->xsh);
    float acc = 0.0f;
#pragma unroll 4
    for (int d = 0; d < Kk; d += 4){
      float4 xv = x4[d >> 2];
      float4 yv = y4[j * (Kk/4) + (d >> 2)];
      float d0 = xv.x - yv.x, d1 = xv.y - yv.y, d2 = xv.z - yv.z, d3 = xv.w - yv.w;
      acc += d0*d0 + d1*d1 + d2*d2 + d3*d3;
    }
    dist[i * 256 + j] = acc;
    int bin = (int)(acc * 2048.0f);
    bin = bin < 0 ? 0 : (bin > 8191 ? 8191 : bin);
    atomicAdd(&sm->hl[bin], 1);
    __syncthreads();
    for (int k = j; k < 8192; k += 256){
      int c = sm->hl[k];
      if (c) atomicAdd(ghist + k, c);
    }
  }
  grid.sync();

  // ================= stage 11: bw (per-block) + score reduction =================
  {
    ScoreSM* sm = reinterpret_cast<ScoreSM*>(SMRAW);
    const int i = bid, j = t;
    sm->xsh[j]  = z[(size_t)i * Kk + j];
    sm->sxsh[j] = score[(size_t)i * Kk + j];
    {
      const int lane = j & 63, w = j >> 6;
      const int base = j * 32;
      int s = 0;
#pragma unroll
      for (int u = 0; u < 32; u++) s += ghist[base + u];
      int sc = s;
#pragma unroll
      for (int m = 1; m < 64; m <<= 1){
        int o = __shfl_up(sc, m, 64);
        if (lane >= m) sc += o;
      }
      if (lane == 63) sm->wt4[w] = sc;
      __syncthreads();
      int off = 0;
      for (int q = 0; q < w; q++) off += sm->wt4[q];
      int cum = sc + off, basex = cum - s;
#pragma unroll
      for (int rr = 0; rr < 2; rr++){
        int rank = 32768 + rr;
        if (basex < rank && cum >= rank){
          int c = basex;
          for (int u = 0; u < 32; u++){
            c += ghist[base + u];
            if (c >= rank){ sm->bres[rr] = base + u; break; }
          }
        }
      }
      __syncthreads();
      if (j == 0){
        float med = 0.5f * ((sm->bres[0] + 0.5f) + (sm->bres[1] + 0.5f)) * (1.0f / 2048.0f);
        float bw = sqrtf(med * 0.5f);
        bw = fminf(fmaxf(bw, 0.1f), 10.0f);
        sm->bw2 = bw * bw;
      }
      __syncthreads();
    }
    const float bw2 = sm->bw2;
    const float4* sy4 = reinterpret_cast<const float4*>(score + (size_t)Bb * Kk);
    const float4* x4  = reinterpret_cast<const float4*>(sm->xsh);
    const float4* sx4 = reinterpret_cast<const float4*>(sm->sxsh);
    float ssy = 0, xsy = 0;
#pragma unroll 4
    for (int d = 0; d < Kk; d += 4){
      float4 xv  = x4[d >> 2];
      float4 sxv = sx4[d >> 2];
      float4 syv = sy4[j * (Kk/4) + (d >> 2)];
      ssy += sxv.x*syv.x + sxv.y*syv.y + sxv.z*syv.z + sxv.w*syv.w;
      xsy += xv.x*syv.x + xv.y*syv.y + xv.z*syv.z + xv.w*syv.w;
    }
    float d2 = dist[i * 256 + j];
    float kv = expf(-d2 / (2.0f * bw2));
    float t1 = kv * ssy;
    float t2 = (xsy - ysy[Bb + j]) * kv / bw2;
    float t3 = d2 * kv / (bw2 * bw2) - kv * (float)Kk / bw2;
    float s = wred(t1 + t2 + t3);
    if (!(j & 63)) sm->red4[j >> 6] = s;
    __syncthreads();
    if (j == 0) atomicAdd(scal + 2, sm->red4[0] + sm->red4[1] + sm->red4[2] + sm->red4[3]);
  }
  grid.sync();

  // ================= stage 12: finalize =================
  if (bid == 0 && t == 0){
    p.out[0] = 0.5f * (scal[0] + scal[1]) * (1.0f/256.0f)
             + 0.1f * scal[2] * (1.0f/65536.0f);
  }
}

extern "C" void kernel_launch(void* const* d_in, const int* in_sizes, int n_in,
                              void* d_out, int out_size, void* d_ws, size_t ws_size,
                              hipStream_t stream) {
  (void)in_sizes; (void)n_in; (void)out_size; (void)ws_size;
  Params prm;
  prm.img  = (const float*)d_in[0];
  prm.txt  = (const float*)d_in[1];
  prm.epsi = (const float*)d_in[2];
  prm.epst = (const float*)d_in[3];
  prm.mask = (const int*)d_in[4];
  prm.eW1i = (const float*)d_in[5];   prm.eb1i = (const float*)d_in[6];
  prm.egi  = (const float*)d_in[7];   prm.ebei = (const float*)d_in[8];
  prm.eW2i = (const float*)d_in[9];   prm.eb2i = (const float*)d_in[10];
  prm.eW1t = (const float*)d_in[11];  prm.eb1t = (const float*)d_in[12];
  prm.egt  = (const float*)d_in[13];  prm.ebet = (const float*)d_in[14];
  prm.eW2t = (const float*)d_in[15];  prm.eb2t = (const float*)d_in[16];
  prm.sW1i = (const float*)d_in[17];  prm.sb1i = (const float*)d_in[18];
  prm.sgi  = (const float*)d_in[19];  prm.sbei = (const float*)d_in[20];
  prm.sW2i = (const float*)d_in[21];  prm.sb2i = (const float*)d_in[22];
  prm.sW1t = (const float*)d_in[23];  prm.sb1t = (const float*)d_in[24];
  prm.sgt  = (const float*)d_in[25];  prm.sbet = (const float*)d_in[26];
  prm.sW2t = (const float*)d_in[27];  prm.sb2t = (const float*)d_in[28];
  prm.ws   = (float*)d_ws;
  prm.out  = (float*)d_out;

  void* kargs[] = { (void*)&prm };
  hipLaunchCooperativeKernel((const void*)k_mega, dim3(256), dim3(256),
                             kargs, 0, stream);
}

// Round 5
// 392.662 us; speedup vs baseline: 1.0018x; 1.0018x over previous
//
#include <hip/hip_runtime.h>
#include <hip/hip_cooperative_groups.h>
#include <math.h>

namespace cg = cooperative_groups;

#define Bb   256
#define Lq   128
#define D1   768
#define Hh   1024
#define Kk   256
#define K2v  512

// ---- ws float offsets ----
#define OFF_EPSG  0                    // 512*256
#define OFF_P     131072               // 2097152 floats (partial arena)
#define OFF_Z     2228224              // 512*256
#define OFF_SCORE 2359296              // 512*256
#define OFF_DIST  2490368              // 65536
#define OFF_HIST  2555904              // 8192 ints
#define OFF_SCAL  2564096              // [0]=kl_i [1]=kl_t [2]=align
#define OFF_YSY   2564104              // 512
#define OFF_SEQL  2564616              // 256 ints
#define OFF_BF    2564880              // ushort arena (16B aligned)

// ---- ushort offsets inside bf arena ----
#define UB_XG   0                      // 512*768
#define UB_HACT 393216                 // 512*1024 (reused 512*512)
#define UB_ZB   917504                 // 512*256
#define UB_WT   1048576                // transposed bf16 weights
#define WT_EW1I 0
#define WT_EW1T 786432
#define WT_EW2I 1572864
#define WT_EW2T 2097152
#define WT_SW1I 2621440
#define WT_SW1T 2752512
#define WT_SW2I 2883584
#define WT_SW2T 3014656

typedef __attribute__((ext_vector_type(8))) short short8v;
typedef __attribute__((ext_vector_type(4))) float f32x4;

__device__ __forceinline__ float wred(float v){
#pragma unroll
  for (int m = 32; m; m >>= 1) v += __shfl_xor(v, m, 64);
  return v;
}
__device__ __forceinline__ int wredi(int v){
#pragma unroll
  for (int m = 32; m; m >>= 1) v += __shfl_xor(v, m, 64);
  return v;
}
__device__ __forceinline__ float gelu_exact(float x){
  return 0.5f * x * (1.0f + erff(x * 0.70710678118654752f));
}
__device__ __forceinline__ ushort f2b(float f){
  union { float f; unsigned u; } v; v.f = f;
  return (ushort)((v.u + 0x7FFFu + ((v.u >> 16) & 1u)) >> 16);
}

struct Params {
  const float *img, *txt, *epsi, *epst;
  const int   *mask;
  const float *eW1i,*eb1i,*egi,*ebei,*eW2i,*eb2i;
  const float *eW1t,*eb1t,*egt,*ebet,*eW2t,*eb2t;
  const float *sW1i,*sb1i,*sgi,*sbei,*sW2i,*sb2i;
  const float *sW1t,*sb1t,*sgt,*sbet,*sW2t,*sb2t;
  float *ws;
  float *out;
};

// shared-memory overlays
struct ConvSM  { float lsf[32][33]; };
struct DistSM  { float xsh[256]; int hl[8192]; };
struct ScoreSM { float xsh[256]; float sxsh[256]; int wt4[4]; int bres[2]; float red4[4]; float bw2; };
struct LNSM    { float2 wsum[4]; };

// ---- MFMA bf16 GEMM stage (K-split partials into P) ----
template<int BM,int KCH,int N,int K>
__device__ __forceinline__ void gemm_stage(
    const ushort* __restrict__ A, const ushort* __restrict__ WTi,
    const ushort* __restrict__ WTt, float* __restrict__ P,
    ushort* LS, int tid, int n0, int r0, int kb, int ks)
{
  constexpr int RPW = BM / 64;
  const int lane = tid & 63, wid = tid >> 6;
  const ushort* WT = (r0 >= 256) ? WTt : WTi;

  f32x4 acc[RPW][4];
#pragma unroll
  for (int s = 0; s < RPW; s++)
#pragma unroll
    for (int c = 0; c < 4; c++) acc[s][c] = (f32x4){0.f,0.f,0.f,0.f};

  const int l15 = lane & 15, kg = lane >> 4;
  const int rdswz = (kg * 16) ^ ((l15 & 3) << 4);

  for (int k0 = kb; k0 < kb + KCH; k0 += 32){
    __syncthreads();
    constexpr int NCHK = (BM + 64) * 4;
#pragma unroll
    for (int i = 0; i < NCHK / 256; i++){
      const int q = (i * 256 + tid) * 16;
      const int row = q >> 6, koff = q & 63;
      const ushort* src = (row < BM)
          ? (A  + (size_t)(r0 + row) * K + k0)
          : (WT + (size_t)(n0 + row - BM) * K + k0);
      short8v v = *reinterpret_cast<const short8v*>(
          reinterpret_cast<const char*>(src) + koff);
      const int dq = (q & ~63) | (koff ^ ((row & 3) << 4));
      *reinterpret_cast<short8v*>(reinterpret_cast<char*>(LS) + dq) = v;
    }
    __syncthreads();
    const char* Ab  = reinterpret_cast<const char*>(LS);
    const char* Bbp = reinterpret_cast<const char*>(LS + BM * 32);
    short8v ar[RPW], bc[4];
#pragma unroll
    for (int s = 0; s < RPW; s++){
      const int row = wid * (RPW * 16) + s * 16 + l15;
      ar[s] = *reinterpret_cast<const short8v*>(Ab + row * 64 + rdswz);
    }
#pragma unroll
    for (int c = 0; c < 4; c++){
      const int col = c * 16 + l15;
      bc[c] = *reinterpret_cast<const short8v*>(Bbp + col * 64 + rdswz);
    }
#pragma unroll
    for (int s = 0; s < RPW; s++)
#pragma unroll
      for (int c = 0; c < 4; c++)
        acc[s][c] = __builtin_amdgcn_mfma_f32_16x16x32_bf16(ar[s], bc[c], acc[s][c], 0, 0, 0);
  }
#pragma unroll
  for (int s = 0; s < RPW; s++)
#pragma unroll
    for (int c = 0; c < 4; c++)
#pragma unroll
      for (int r = 0; r < 4; r++){
        const int row = r0 + wid * (RPW * 16) + s * 16 + kg * 4 + r;
        const int col = n0 + c * 16 + l15;
        P[((size_t)ks * 512 + row) * N + col] = acc[s][c][r];
      }
}

// ---- LN+gelu over W-wide row, summing NS partials + bias -> bf16 ----
template<int W, int NS>
__device__ __forceinline__ void ln_row(
    const float* __restrict__ P, int row,
    const float* __restrict__ b1, const float* __restrict__ g,
    const float* __restrict__ be, ushort* __restrict__ hb,
    LNSM* sm, int t)
{
  // W/4 float4 per row; threads t < W/4 active
  float4 v = make_float4(0,0,0,0);
  if (t < W/4){
    const float4* P4 = reinterpret_cast<const float4*>(P);
#pragma unroll
    for (int s = 0; s < NS; s++){
      float4 p = P4[((size_t)s * 512 + row) * (W/4) + t];
      v.x += p.x; v.y += p.y; v.z += p.z; v.w += p.w;
    }
    float4 bb = reinterpret_cast<const float4*>(b1)[t];
    v.x += bb.x; v.y += bb.y; v.z += bb.z; v.w += bb.w;
  }
  float ps = wred(v.x + v.y + v.z + v.w);
  float pq = wred(v.x*v.x + v.y*v.y + v.z*v.z + v.w*v.w);
  if (!(t & 63)) sm->wsum[t >> 6] = make_float2(ps, pq);
  __syncthreads();
  float S = 0, Q = 0;
#pragma unroll
  for (int i = 0; i < (W == 1024 ? 4 : 2); i++){ S += sm->wsum[i].x; Q += sm->wsum[i].y; }
  if (t < W/4){
    float mean = S * (1.0f/W);
    float rstd = rsqrtf(Q * (1.0f/W) - mean*mean + 1e-5f);
    float4 gv  = reinterpret_cast<const float4*>(g)[t];
    float4 bev = reinterpret_cast<const float4*>(be)[t];
    ushort4 o;
    o.x = f2b(gelu_exact((v.x - mean)*rstd*gv.x + bev.x));
    o.y = f2b(gelu_exact((v.y - mean)*rstd*gv.y + bev.y));
    o.z = f2b(gelu_exact((v.z - mean)*rstd*gv.z + bev.z));
    o.w = f2b(gelu_exact((v.w - mean)*rstd*gv.w + bev.w));
    reinterpret_cast<ushort4*>(hb)[(size_t)row * (W/4) + t] = o;
  }
}

__global__ __launch_bounds__(256) void k_mega(Params p)
{
  __shared__ __align__(16) char SMRAW[sizeof(DistSM)];
  __shared__ int s_last;
  cg::grid_group grid = cg::this_grid();

  const int bid = blockIdx.x;          // 0..255
  const int t   = threadIdx.x;         // 0..255

  float*  ws    = p.ws;
  float*  epsg  = ws + OFF_EPSG;
  float*  P     = ws + OFF_P;
  float*  z     = ws + OFF_Z;
  float*  score = ws + OFF_SCORE;
  float*  dist  = ws + OFF_DIST;
  int*    ghist = (int*)(ws + OFF_HIST);
  float*  scal  = ws + OFF_SCAL;
  float*  ysy   = ws + OFF_YSY;
  int*    seql  = (int*)(ws + OFF_SEQL);
  ushort* ub    = (ushort*)(ws + OFF_BF);
  ushort* xgb   = ub + UB_XG;
  ushort* hb    = ub + UB_HACT;
  ushort* zb    = ub + UB_ZB;
  ushort* wt    = ub + UB_WT;

  // ================= stage 1: prep (seql, zero, gather) + weight conv =================
  {
    // seq_last for row bid
    int s = 0;
    if (t < 32){
      int4 v = reinterpret_cast<const int4*>(p.mask + bid * Lq)[t];
      s = v.x + v.y + v.z + v.w;
    }
    if (t < 64){
      int tot = wredi(s);
      if (t == 0){ seql[bid] = tot - 1; s_last = tot - 1; }
    }
    // zero hist / scal
    if (t < 8) reinterpret_cast<int4*>(ghist)[bid * 8 + t] = make_int4(0,0,0,0);
    if (bid == 0 && t < 8) scal[t] = 0.0f;
    __syncthreads();
    const int last = s_last;
    // gather + convert x rows
    if (t < 192){
      float4 v = reinterpret_cast<const float4*>(p.img + (size_t)(bid*Lq+last)*D1)[t];
      ushort4 o; o.x=f2b(v.x); o.y=f2b(v.y); o.z=f2b(v.z); o.w=f2b(v.w);
      reinterpret_cast<ushort4*>(xgb + (size_t)bid*D1)[t] = o;
      float4 w = reinterpret_cast<const float4*>(p.txt + (size_t)(bid*Lq+last)*D1)[t];
      ushort4 q; q.x=f2b(w.x); q.y=f2b(w.y); q.z=f2b(w.z); q.w=f2b(w.w);
      reinterpret_cast<ushort4*>(xgb + (size_t)(Bb+bid)*D1)[t] = q;
    }
    if (t < 64){
      reinterpret_cast<float4*>(epsg + (size_t)bid*Kk)[t] =
        reinterpret_cast<const float4*>(p.epsi + (size_t)(bid*Lq+last)*Kk)[t];
      reinterpret_cast<float4*>(epsg + (size_t)(Bb+bid)*Kk)[t] =
        reinterpret_cast<const float4*>(p.epst + (size_t)(bid*Lq+last)*Kk)[t];
    }
    // weight transpose-convert: 3072 tiles, 12 per block
    ConvSM* cs = reinterpret_cast<ConvSM*>(SMRAW);
    for (int it = 0; it < 12; ++it){
      const int wb = bid + it * 256;
      const float* src; ushort* dst; int Kd, Nd, ti;
      if      (wb < 768){  src=p.eW1i; dst=wt+WT_EW1I; Kd=768;  Nd=1024; ti=wb; }
      else if (wb < 1536){ src=p.eW1t; dst=wt+WT_EW1T; Kd=768;  Nd=1024; ti=wb-768; }
      else if (wb < 2048){ src=p.eW2i; dst=wt+WT_EW2I; Kd=1024; Nd=512;  ti=wb-1536; }
      else if (wb < 2560){ src=p.eW2t; dst=wt+WT_EW2T; Kd=1024; Nd=512;  ti=wb-2048; }
      else if (wb < 2688){ src=p.sW1i; dst=wt+WT_SW1I; Kd=256;  Nd=512;  ti=wb-2560; }
      else if (wb < 2816){ src=p.sW1t; dst=wt+WT_SW1T; Kd=256;  Nd=512;  ti=wb-2688; }
      else if (wb < 2944){ src=p.sW2i; dst=wt+WT_SW2I; Kd=512;  Nd=256;  ti=wb-2816; }
      else               { src=p.sW2t; dst=wt+WT_SW2T; Kd=512;  Nd=256;  ti=wb-2944; }
      const int ntile = Nd / 32;
      const int k0 = (ti / ntile) * 32, n0 = (ti % ntile) * 32;
      const int r = t >> 3, q = t & 7;
      float4 v = reinterpret_cast<const float4*>(src + (size_t)(k0+r)*Nd + n0)[q];
      __syncthreads();
      cs->lsf[r][q*4+0]=v.x; cs->lsf[r][q*4+1]=v.y; cs->lsf[r][q*4+2]=v.z; cs->lsf[r][q*4+3]=v.w;
      __syncthreads();
      ushort4 o;
      o.x = f2b(cs->lsf[q*4+0][r]); o.y = f2b(cs->lsf[q*4+1][r]);
      o.z = f2b(cs->lsf[q*4+2][r]); o.w = f2b(cs->lsf[q*4+3][r]);
      *reinterpret_cast<ushort4*>(dst + (size_t)(n0+r)*Kd + k0 + q*4) = o;
    }
  }
  grid.sync();

  // ================= stage 2: enc GEMM1 [512,768]@[768,1024], ks=4 =================
  {
    ushort* LS = reinterpret_cast<ushort*>(SMRAW);
    const int n0 = (bid & 15) * 64, m = (bid >> 4) & 3, ks = bid >> 6;
    gemm_stage<128,192,1024,768>(xgb, wt+WT_EW1I, wt+WT_EW1T, P, LS, t, n0, m*128, ks*192, ks);
  }
  grid.sync();

  // ================= stage 3: LN1 (1024-wide, 4 partials) =================
  {
    LNSM* sm = reinterpret_cast<LNSM*>(SMRAW);
#pragma unroll
    for (int rr = 0; rr < 2; rr++){
      const int row = bid + rr * 256;
      __syncthreads();
      ln_row<1024,4>(P, row, row >= 256 ? p.eb1t : p.eb1i,
                     row >= 256 ? p.egt : p.egi,
                     row >= 256 ? p.ebet : p.ebei, hb, sm, t);
    }
  }
  grid.sync();

  // ================= stage 4: enc GEMM2 [512,1024]@[1024,512], ks=8 =================
  {
    ushort* LS = reinterpret_cast<ushort*>(SMRAW);
    const int n0 = (bid & 7) * 64, m = (bid >> 3) & 3, ks = bid >> 5;
    gemm_stage<128,128,512,1024>(hb, wt+WT_EW2I, wt+WT_EW2T, P, LS, t, n0, m*128, ks*128, ks);
  }
  grid.sync();

  // ================= stage 5: reparam + normalize + KL (8 partials) =================
  {
    const int wv = t >> 6, lane = t & 63;
    if (wv < 2 && lane < 64){
      const int row = bid + wv * 256;
      const float* b2 = row >= 256 ? p.eb2t : p.eb2i;
      const float4* P4 = reinterpret_cast<const float4*>(P);
      float4 mu = make_float4(0,0,0,0), lv = make_float4(0,0,0,0);
#pragma unroll
      for (int s = 0; s < 8; s++){
        float4 a = P4[((size_t)s * 512 + row) * (K2v/4) + lane];
        float4 c = P4[((size_t)s * 512 + row) * (K2v/4) + 64 + lane];
        mu.x += a.x; mu.y += a.y; mu.z += a.z; mu.w += a.w;
        lv.x += c.x; lv.y += c.y; lv.z += c.z; lv.w += c.w;
      }
      float4 bm = reinterpret_cast<const float4*>(b2)[lane];
      float4 bl = reinterpret_cast<const float4*>(b2)[64 + lane];
      mu.x += bm.x; mu.y += bm.y; mu.z += bm.z; mu.w += bm.w;
      lv.x += bl.x; lv.y += bl.y; lv.z += bl.z; lv.w += bl.w;
      float4 ev = reinterpret_cast<const float4*>(epsg)[(size_t)row * 64 + lane];
      float z0 = mu.x + ev.x * expf(0.5f * lv.x);
      float z1 = mu.y + ev.y * expf(0.5f * lv.y);
      float z2 = mu.z + ev.z * expf(0.5f * lv.z);
      float z3 = mu.w + ev.w * expf(0.5f * lv.w);
      float s2 = wred(z0*z0 + z1*z1 + z2*z2 + z3*z3);
      float klp = (1.0f + lv.x - mu.x*mu.x - expf(lv.x))
                + (1.0f + lv.y - mu.y*mu.y - expf(lv.y))
                + (1.0f + lv.z - mu.z*mu.z - expf(lv.z))
                + (1.0f + lv.w - mu.w*mu.w - expf(lv.w));
      float klt = wred(klp);
      float inv = 1.0f / fmaxf(sqrtf(s2), 1e-12f);
      float4 zv = make_float4(z0*inv, z1*inv, z2*inv, z3*inv);
      reinterpret_cast<float4*>(z)[(size_t)row * 64 + lane] = zv;
      ushort4 o; o.x=f2b(zv.x); o.y=f2b(zv.y); o.z=f2b(zv.z); o.w=f2b(zv.w);
      reinterpret_cast<ushort4*>(zb)[(size_t)row * 64 + lane] = o;
      if (lane == 0) atomicAdd(scal + (row >= 256 ? 1 : 0), -0.5f * klt);
    }
  }
  grid.sync();

  // ================= stage 6: sc GEMM1 [512,256]@[256,512], ks=4 =================
  {
    ushort* LS = reinterpret_cast<ushort*>(SMRAW);
    const int n0 = (bid & 7) * 64, m = (bid >> 3) & 7, ks = bid >> 6;
    gemm_stage<64,64,512,256>(zb, wt+WT_SW1I, wt+WT_SW1T, P, LS, t, n0, m*64, ks*64, ks);
  }
  grid.sync();

  // ================= stage 7: LN2 (512-wide, 4 partials) =================
  {
    LNSM* sm = reinterpret_cast<LNSM*>(SMRAW);
#pragma unroll
    for (int rr = 0; rr < 2; rr++){
      const int row = bid + rr * 256;
      __syncthreads();
      ln_row<512,4>(P, row, row >= 256 ? p.sb1t : p.sb1i,
                    row >= 256 ? p.sgt : p.sgi,
                    row >= 256 ? p.sbet : p.sbei, hb, sm, t);
    }
  }
  grid.sync();

  // ================= stage 8: sc GEMM2 [512,512]@[512,256], ks=8 =================
  {
    ushort* LS = reinterpret_cast<ushort*>(SMRAW);
    const int n0 = (bid & 3) * 64, m = (bid >> 2) & 7, ks = bid >> 5;
    gemm_stage<64,64,256,512>(hb, wt+WT_SW2I, wt+WT_SW2T, P, LS, t, n0, m*64, ks*64, ks);
  }
  grid.sync();

  // ================= stage 9: score partial-sum (8) + bias; ysy =================
  {
    const int wv = t >> 6, lane = t & 63;
    if (wv < 2){
      const int row = bid + wv * 256;
      const float* b2 = row >= 256 ? p.sb2t : p.sb2i;
      const float4* P4 = reinterpret_cast<const float4*>(P);
      float4 v = make_float4(0,0,0,0);
#pragma unroll
      for (int s = 0; s < 8; s++){
        float4 q = P4[((size_t)s * 512 + row) * (Kk/4) + lane];
        v.x += q.x; v.y += q.y; v.z += q.z; v.w += q.w;
      }
      float4 bb = reinterpret_cast<const float4*>(b2)[lane];
      v.x += bb.x; v.y += bb.y; v.z += bb.z; v.w += bb.w;
      reinterpret_cast<float4*>(score)[(size_t)row * 64 + lane] = v;
      float4 zv = reinterpret_cast<const float4*>(z)[(size_t)row * 64 + lane];
      float yp = wred(zv.x*v.x + zv.y*v.y + zv.z*v.z + zv.w*v.w);
      if (lane == 0) ysy[row] = yp;
    }
  }
  grid.sync();

  // ================= stage 10: pairwise dist + histogram =================
  {
    DistSM* sm = reinterpret_cast<DistSM*>(SMRAW);
    const int i = bid, j = t;
    sm->xsh[j] = z[(size_t)i * Kk + j];
#pragma unroll
    for (int k = j; k < 8192; k += 256) sm->hl[k] = 0;
    __syncthreads();
    const float4* y4 = reinterpret_cast<const float4*>(z + (size_t)Bb * Kk);
    const float4* x4 = reinterpret_cast<const float4*>(sm->xsh);
    float acc = 0.0f;
#pragma unroll 4
    for (int d = 0; d < Kk; d += 4){
      float4 xv = x4[d >> 2];
      float4 yv = y4[j * (Kk/4) + (d >> 2)];
      float d0 = xv.x - yv.x, d1 = xv.y - yv.y, d2 = xv.z - yv.z, d3 = xv.w - yv.w;
      acc += d0*d0 + d1*d1 + d2*d2 + d3*d3;
    }
    dist[i * 256 + j] = acc;
    int bin = (int)(acc * 2048.0f);
    bin = bin < 0 ? 0 : (bin > 8191 ? 8191 : bin);
    atomicAdd(&sm->hl[bin], 1);
    __syncthreads();
    for (int k = j; k < 8192; k += 256){
      int c = sm->hl[k];
      if (c) atomicAdd(ghist + k, c);
    }
  }
  grid.sync();

  // ================= stage 11: bw (per-block) + score reduction =================
  {
    ScoreSM* sm = reinterpret_cast<ScoreSM*>(SMRAW);
    const int i = bid, j = t;
    sm->xsh[j]  = z[(size_t)i * Kk + j];
    sm->sxsh[j] = score[(size_t)i * Kk + j];
    {
      const int lane = j & 63, w = j >> 6;
      const int base = j * 32;
      int s = 0;
#pragma unroll
      for (int u = 0; u < 32; u++) s += ghist[base + u];
      int sc = s;
#pragma unroll
      for (int m = 1; m < 64; m <<= 1){
        int o = __shfl_up(sc, m, 64);
        if (lane >= m) sc += o;
      }
      if (lane == 63) sm->wt4[w] = sc;
      __syncthreads();
      int off = 0;
      for (int q = 0; q < w; q++) off += sm->wt4[q];
      int cum = sc + off, basex = cum - s;
#pragma unroll
      for (int rr = 0; rr < 2; rr++){
        int rank = 32768 + rr;
        if (basex < rank && cum >= rank){
          int c = basex;
          for (int u = 0; u < 32; u++){
            c += ghist[base + u];
            if (c >= rank){ sm->bres[rr] = base + u; break; }
          }
        }
      }
      __syncthreads();
      if (j == 0){
        float med = 0.5f * ((sm->bres[0] + 0.5f) + (sm->bres[1] + 0.5f)) * (1.0f / 2048.0f);
        float bw = sqrtf(med * 0.5f);
        bw = fminf(fmaxf(bw, 0.1f), 10.0f);
        sm->bw2 = bw * bw;
      }
      __syncthreads();
    }
    const float bw2 = sm->bw2;
    const float4* sy4 = reinterpret_cast<const float4*>(score + (size_t)Bb * Kk);
    const float4* x4  = reinterpret_cast<const float4*>(sm->xsh);
    const float4* sx4 = reinterpret_cast<const float4*>(sm->sxsh);
    float ssy = 0, xsy = 0;
#pragma unroll 4
    for (int d = 0; d < Kk; d += 4){
      float4 xv  = x4[d >> 2];
      float4 sxv = sx4[d >> 2];
      float4 syv = sy4[j * (Kk/4) + (d >> 2)];
      ssy += sxv.x*syv.x + sxv.y*syv.y + sxv.z*syv.z + sxv.w*syv.w;
      xsy += xv.x*syv.x + xv.y*syv.y + xv.z*syv.z + xv.w*syv.w;
    }
    float d2 = dist[i * 256 + j];
    float kv = expf(-d2 / (2.0f * bw2));
    float t1 = kv * ssy;
    float t2 = (xsy - ysy[Bb + j]) * kv / bw2;
    float t3 = d2 * kv / (bw2 * bw2) - kv * (float)Kk / bw2;
    float s = wred(t1 + t2 + t3);
    if (!(j & 63)) sm->red4[j >> 6] = s;
    __syncthreads();
    if (j == 0) atomicAdd(scal + 2, sm->red4[0] + sm->red4[1] + sm->red4[2] + sm->red4[3]);
  }
  grid.sync();

  // ================= stage 12: finalize =================
  if (bid == 0 && t == 0){
    p.out[0] = 0.5f * (scal[0] + scal[1]) * (1.0f/256.0f)
             + 0.1f * scal[2] * (1.0f/65536.0f);
  }
}

extern "C" void kernel_launch(void* const* d_in, const int* in_sizes, int n_in,
                              void* d_out, int out_size, void* d_ws, size_t ws_size,
                              hipStream_t stream) {
  (void)in_sizes; (void)n_in; (void)out_size; (void)ws_size;
  Params prm;
  prm.img  = (const float*)d_in[0];
  prm.txt  = (const float*)d_in[1];
  prm.epsi = (const float*)d_in[2];
  prm.epst = (const float*)d_in[3];
  prm.mask = (const int*)d_in[4];
  prm.eW1i = (const float*)d_in[5];   prm.eb1i = (const float*)d_in[6];
  prm.egi  = (const float*)d_in[7];   prm.ebei = (const float*)d_in[8];
  prm.eW2i = (const float*)d_in[9];   prm.eb2i = (const float*)d_in[10];
  prm.eW1t = (const float*)d_in[11];  prm.eb1t = (const float*)d_in[12];
  prm.egt  = (const float*)d_in[13];  prm.ebet = (const float*)d_in[14];
  prm.eW2t = (const float*)d_in[15];  prm.eb2t = (const float*)d_in[16];
  prm.sW1i = (const float*)d_in[17];  prm.sb1i = (const float*)d_in[18];
  prm.sgi  = (const float*)d_in[19];  prm.sbei = (const float*)d_in[20];
  prm.sW2i = (const float*)d_in[21];  prm.sb2i = (const float*)d_in[22];
  prm.sW1t = (const float*)d_in[23];  prm.sb1t = (const float*)d_in[24];
  prm.sgt  = (const float*)d_in[25];  prm.sbet = (const float*)d_in[26];
  prm.sW2t = (const float*)d_in[27];  prm.sb2t = (const float*)d_in[28];
  prm.ws   = (float*)d_ws;
  prm.out  = (float*)d_out;

  void* kargs[] = { (void*)&prm };
  hipLaunchCooperativeKernel((const void*)k_mega, dim3(256), dim3(256),
                             kargs, 0, stream);
}

// Round 6
// 391.977 us; speedup vs baseline: 1.0035x; 1.0017x over previous
//
#include <hip/hip_runtime.h>
#include <hip/hip_cooperative_groups.h>
#include <math.h>

namespace cg = cooperative_groups;

#define Bb   256
#define Lq   128
#define D1   768
#define Hh   1024
#define Kk   256
#define K2v  512

// ---- ws float offsets ----
#define OFF_EPSG  0                    // 512*256
#define OFF_P     131072               // 2097152 floats (partial arena)
#define OFF_Z     2228224              // 512*256
#define OFF_SCORE 2359296              // 512*256
#define OFF_DIST  2490368              // 65536
#define OFF_HIST  2555904              // 8192 ints
#define OFF_SCAL  2564096              // [0]=kl_i [1]=kl_t [2]=align
#define OFF_YSY   2564104              // 512
#define OFF_SEQL  2564616              // 256 ints
#define OFF_BF    2564880              // ushort arena (16B aligned)

// ---- ushort offsets inside bf arena ----
#define UB_XG   0                      // 512*768
#define UB_HACT 393216                 // 512*1024 (reused 512*512)
#define UB_ZB   917504                 // 512*256
#define UB_WT   1048576                // transposed bf16 weights
#define WT_EW1I 0
#define WT_EW1T 786432
#define WT_EW2I 1572864
#define WT_EW2T 2097152
#define WT_SW1I 2621440
#define WT_SW1T 2752512
#define WT_SW2I 2883584
#define WT_SW2T 3014656

typedef __attribute__((ext_vector_type(8))) short short8v;
typedef __attribute__((ext_vector_type(4))) float f32x4;

__device__ __forceinline__ float wred(float v){
#pragma unroll
  for (int m = 32; m; m >>= 1) v += __shfl_xor(v, m, 64);
  return v;
}
__device__ __forceinline__ int wredi(int v){
#pragma unroll
  for (int m = 32; m; m >>= 1) v += __shfl_xor(v, m, 64);
  return v;
}
__device__ __forceinline__ float gelu_exact(float x){
  return 0.5f * x * (1.0f + erff(x * 0.70710678118654752f));
}
__device__ __forceinline__ ushort f2b(float f){
  union { float f; unsigned u; } v; v.f = f;
  return (ushort)((v.u + 0x7FFFu + ((v.u >> 16) & 1u)) >> 16);
}

struct Params {
  const float *img, *txt, *epsi, *epst;
  const int   *mask;
  const float *eW1i,*eb1i,*egi,*ebei,*eW2i,*eb2i;
  const float *eW1t,*eb1t,*egt,*ebet,*eW2t,*eb2t;
  const float *sW1i,*sb1i,*sgi,*sbei,*sW2i,*sb2i;
  const float *sW1t,*sb1t,*sgt,*sbet,*sW2t,*sb2t;
  float *ws;
  float *out;
};

// shared-memory overlays
struct ConvSM  { float lsf[32][33]; };
struct DistSM  { float xsh[256]; int hl[8192]; };
struct ScoreSM { float xsh[256]; float sxsh[256]; int wt4[4]; int bres[2]; float red4[4]; float bw2; };
struct LNSM    { float2 wsum[4]; };

// ---- MFMA bf16 GEMM stage (K-split partials into P) ----
template<int BM,int KCH,int N,int K>
__device__ __forceinline__ void gemm_stage(
    const ushort* __restrict__ A, const ushort* __restrict__ WTi,
    const ushort* __restrict__ WTt, float* __restrict__ P,
    ushort* LS, int tid, int n0, int r0, int kb, int ks)
{
  constexpr int RPW = BM / 64;
  const int lane = tid & 63, wid = tid >> 6;
  const ushort* WT = (r0 >= 256) ? WTt : WTi;

  f32x4 acc[RPW][4];
#pragma unroll
  for (int s = 0; s < RPW; s++)
#pragma unroll
    for (int c = 0; c < 4; c++) acc[s][c] = (f32x4){0.f,0.f,0.f,0.f};

  const int l15 = lane & 15, kg = lane >> 4;
  const int rdswz = (kg * 16) ^ ((l15 & 3) << 4);

  for (int k0 = kb; k0 < kb + KCH; k0 += 32){
    __syncthreads();
    constexpr int NCHK = (BM + 64) * 4;
#pragma unroll
    for (int i = 0; i < NCHK / 256; i++){
      const int q = (i * 256 + tid) * 16;
      const int row = q >> 6, koff = q & 63;
      const ushort* src = (row < BM)
          ? (A  + (size_t)(r0 + row) * K + k0)
          : (WT + (size_t)(n0 + row - BM) * K + k0);
      short8v v = *reinterpret_cast<const short8v*>(
          reinterpret_cast<const char*>(src) + koff);
      const int dq = (q & ~63) | (koff ^ ((row & 3) << 4));
      *reinterpret_cast<short8v*>(reinterpret_cast<char*>(LS) + dq) = v;
    }
    __syncthreads();
    const char* Ab  = reinterpret_cast<const char*>(LS);
    const char* Bbp = reinterpret_cast<const char*>(LS + BM * 32);
    short8v ar[RPW], bc[4];
#pragma unroll
    for (int s = 0; s < RPW; s++){
      const int row = wid * (RPW * 16) + s * 16 + l15;
      ar[s] = *reinterpret_cast<const short8v*>(Ab + row * 64 + rdswz);
    }
#pragma unroll
    for (int c = 0; c < 4; c++){
      const int col = c * 16 + l15;
      bc[c] = *reinterpret_cast<const short8v*>(Bbp + col * 64 + rdswz);
    }
#pragma unroll
    for (int s = 0; s < RPW; s++)
#pragma unroll
      for (int c = 0; c < 4; c++)
        acc[s][c] = __builtin_amdgcn_mfma_f32_16x16x32_bf16(ar[s], bc[c], acc[s][c], 0, 0, 0);
  }
#pragma unroll
  for (int s = 0; s < RPW; s++)
#pragma unroll
    for (int c = 0; c < 4; c++)
#pragma unroll
      for (int r = 0; r < 4; r++){
        const int row = r0 + wid * (RPW * 16) + s * 16 + kg * 4 + r;
        const int col = n0 + c * 16 + l15;
        P[((size_t)ks * 512 + row) * N + col] = acc[s][c][r];
      }
}

// ---- LN+gelu over W-wide row, summing NS partials + bias -> bf16 ----
template<int W, int NS>
__device__ __forceinline__ void ln_row(
    const float* __restrict__ P, int row,
    const float* __restrict__ b1, const float* __restrict__ g,
    const float* __restrict__ be, ushort* __restrict__ hb,
    LNSM* sm, int t)
{
  // W/4 float4 per row; threads t < W/4 active
  float4 v = make_float4(0,0,0,0);
  if (t < W/4){
    const float4* P4 = reinterpret_cast<const float4*>(P);
#pragma unroll
    for (int s = 0; s < NS; s++){
      float4 p = P4[((size_t)s * 512 + row) * (W/4) + t];
      v.x += p.x; v.y += p.y; v.z += p.z; v.w += p.w;
    }
    float4 bb = reinterpret_cast<const float4*>(b1)[t];
    v.x += bb.x; v.y += bb.y; v.z += bb.z; v.w += bb.w;
  }
  float ps = wred(v.x + v.y + v.z + v.w);
  float pq = wred(v.x*v.x + v.y*v.y + v.z*v.z + v.w*v.w);
  if (!(t & 63)) sm->wsum[t >> 6] = make_float2(ps, pq);
  __syncthreads();
  float S = 0, Q = 0;
#pragma unroll
  for (int i = 0; i < (W == 1024 ? 4 : 2); i++){ S += sm->wsum[i].x; Q += sm->wsum[i].y; }
  if (t < W/4){
    float mean = S * (1.0f/W);
    float rstd = rsqrtf(Q * (1.0f/W) - mean*mean + 1e-5f);
    float4 gv  = reinterpret_cast<const float4*>(g)[t];
    float4 bev = reinterpret_cast<const float4*>(be)[t];
    ushort4 o;
    o.x = f2b(gelu_exact((v.x - mean)*rstd*gv.x + bev.x));
    o.y = f2b(gelu_exact((v.y - mean)*rstd*gv.y + bev.y));
    o.z = f2b(gelu_exact((v.z - mean)*rstd*gv.z + bev.z));
    o.w = f2b(gelu_exact((v.w - mean)*rstd*gv.w + bev.w));
    reinterpret_cast<ushort4*>(hb)[(size_t)row * (W/4) + t] = o;
  }
}

__global__ __launch_bounds__(256) void k_mega(Params p)
{
  __shared__ __align__(16) char SMRAW[sizeof(DistSM)];
  __shared__ int s_last;
  cg::grid_group grid = cg::this_grid();

  const int bid = blockIdx.x;          // 0..255
  const int t   = threadIdx.x;         // 0..255

  float*  ws    = p.ws;
  float*  epsg  = ws + OFF_EPSG;
  float*  P     = ws + OFF_P;
  float*  z     = ws + OFF_Z;
  float*  score = ws + OFF_SCORE;
  float*  dist  = ws + OFF_DIST;
  int*    ghist = (int*)(ws + OFF_HIST);
  float*  scal  = ws + OFF_SCAL;
  float*  ysy   = ws + OFF_YSY;
  int*    seql  = (int*)(ws + OFF_SEQL);
  ushort* ub    = (ushort*)(ws + OFF_BF);
  ushort* xgb   = ub + UB_XG;
  ushort* hb    = ub + UB_HACT;
  ushort* zb    = ub + UB_ZB;
  ushort* wt    = ub + UB_WT;

  // ================= stage 1: prep (seql, zero, gather) + weight conv =================
  {
    // seq_last for row bid
    int s = 0;
    if (t < 32){
      int4 v = reinterpret_cast<const int4*>(p.mask + bid * Lq)[t];
      s = v.x + v.y + v.z + v.w;
    }
    if (t < 64){
      int tot = wredi(s);
      if (t == 0){ seql[bid] = tot - 1; s_last = tot - 1; }
    }
    // zero hist / scal
    if (t < 8) reinterpret_cast<int4*>(ghist)[bid * 8 + t] = make_int4(0,0,0,0);
    if (bid == 0 && t < 8) scal[t] = 0.0f;
    __syncthreads();
    const int last = s_last;
    // gather + convert x rows
    if (t < 192){
      float4 v = reinterpret_cast<const float4*>(p.img + (size_t)(bid*Lq+last)*D1)[t];
      ushort4 o; o.x=f2b(v.x); o.y=f2b(v.y); o.z=f2b(v.z); o.w=f2b(v.w);
      reinterpret_cast<ushort4*>(xgb + (size_t)bid*D1)[t] = o;
      float4 w = reinterpret_cast<const float4*>(p.txt + (size_t)(bid*Lq+last)*D1)[t];
      ushort4 q; q.x=f2b(w.x); q.y=f2b(w.y); q.z=f2b(w.z); q.w=f2b(w.w);
      reinterpret_cast<ushort4*>(xgb + (size_t)(Bb+bid)*D1)[t] = q;
    }
    if (t < 64){
      reinterpret_cast<float4*>(epsg + (size_t)bid*Kk)[t] =
        reinterpret_cast<const float4*>(p.epsi + (size_t)(bid*Lq+last)*Kk)[t];
      reinterpret_cast<float4*>(epsg + (size_t)(Bb+bid)*Kk)[t] =
        reinterpret_cast<const float4*>(p.epst + (size_t)(bid*Lq+last)*Kk)[t];
    }
    // weight transpose-convert: 3072 tiles, 12 per block
    ConvSM* cs = reinterpret_cast<ConvSM*>(SMRAW);
    for (int it = 0; it < 12; ++it){
      const int wb = bid + it * 256;
      const float* src; ushort* dst; int Kd, Nd, ti;
      if      (wb < 768){  src=p.eW1i; dst=wt+WT_EW1I; Kd=768;  Nd=1024; ti=wb; }
      else if (wb < 1536){ src=p.eW1t; dst=wt+WT_EW1T; Kd=768;  Nd=1024; ti=wb-768; }
      else if (wb < 2048){ src=p.eW2i; dst=wt+WT_EW2I; Kd=1024; Nd=512;  ti=wb-1536; }
      else if (wb < 2560){ src=p.eW2t; dst=wt+WT_EW2T; Kd=1024; Nd=512;  ti=wb-2048; }
      else if (wb < 2688){ src=p.sW1i; dst=wt+WT_SW1I; Kd=256;  Nd=512;  ti=wb-2560; }
      else if (wb < 2816){ src=p.sW1t; dst=wt+WT_SW1T; Kd=256;  Nd=512;  ti=wb-2688; }
      else if (wb < 2944){ src=p.sW2i; dst=wt+WT_SW2I; Kd=512;  Nd=256;  ti=wb-2816; }
      else               { src=p.sW2t; dst=wt+WT_SW2T; Kd=512;  Nd=256;  ti=wb-2944; }
      const int ntile = Nd / 32;
      const int k0 = (ti / ntile) * 32, n0 = (ti % ntile) * 32;
      const int r = t >> 3, q = t & 7;
      float4 v = reinterpret_cast<const float4*>(src + (size_t)(k0+r)*Nd + n0)[q];
      __syncthreads();
      cs->lsf[r][q*4+0]=v.x; cs->lsf[r][q*4+1]=v.y; cs->lsf[r][q*4+2]=v.z; cs->lsf[r][q*4+3]=v.w;
      __syncthreads();
      ushort4 o;
      o.x = f2b(cs->lsf[q*4+0][r]); o.y = f2b(cs->lsf[q*4+1][r]);
      o.z = f2b(cs->lsf[q*4+2][r]); o.w = f2b(cs->lsf[q*4+3][r]);
      *reinterpret_cast<ushort4*>(dst + (size_t)(n0+r)*Kd + k0 + q*4) = o;
    }
  }
  grid.sync();

  // ================= stage 2: enc GEMM1 [512,768]@[768,1024], ks=4 =================
  {
    ushort* LS = reinterpret_cast<ushort*>(SMRAW);
    const int n0 = (bid & 15) * 64, m = (bid >> 4) & 3, ks = bid >> 6;
    gemm_stage<128,192,1024,768>(xgb, wt+WT_EW1I, wt+WT_EW1T, P, LS, t, n0, m*128, ks*192, ks);
  }
  grid.sync();

  // ================= stage 3: LN1 (1024-wide, 4 partials) =================
  {
    LNSM* sm = reinterpret_cast<LNSM*>(SMRAW);
#pragma unroll
    for (int rr = 0; rr < 2; rr++){
      const int row = bid + rr * 256;
      __syncthreads();
      ln_row<1024,4>(P, row, row >= 256 ? p.eb1t : p.eb1i,
                     row >= 256 ? p.egt : p.egi,
                     row >= 256 ? p.ebet : p.ebei, hb, sm, t);
    }
  }
  grid.sync();

  // ================= stage 4: enc GEMM2 [512,1024]@[1024,512], ks=8 =================
  {
    ushort* LS = reinterpret_cast<ushort*>(SMRAW);
    const int n0 = (bid & 7) * 64, m = (bid >> 3) & 3, ks = bid >> 5;
    gemm_stage<128,128,512,1024>(hb, wt+WT_EW2I, wt+WT_EW2T, P, LS, t, n0, m*128, ks*128, ks);
  }
  grid.sync();

  // ================= stage 5: reparam + normalize + KL (8 partials) =================
  {
    const int wv = t >> 6, lane = t & 63;
    if (wv < 2 && lane < 64){
      const int row = bid + wv * 256;
      const float* b2 = row >= 256 ? p.eb2t : p.eb2i;
      const float4* P4 = reinterpret_cast<const float4*>(P);
      float4 mu = make_float4(0,0,0,0), lv = make_float4(0,0,0,0);
#pragma unroll
      for (int s = 0; s < 8; s++){
        float4 a = P4[((size_t)s * 512 + row) * (K2v/4) + lane];
        float4 c = P4[((size_t)s * 512 + row) * (K2v/4) + 64 + lane];
        mu.x += a.x; mu.y += a.y; mu.z += a.z; mu.w += a.w;
        lv.x += c.x; lv.y += c.y; lv.z += c.z; lv.w += c.w;
      }
      float4 bm = reinterpret_cast<const float4*>(b2)[lane];
      float4 bl = reinterpret_cast<const float4*>(b2)[64 + lane];
      mu.x += bm.x; mu.y += bm.y; mu.z += bm.z; mu.w += bm.w;
      lv.x += bl.x; lv.y += bl.y; lv.z += bl.z; lv.w += bl.w;
      float4 ev = reinterpret_cast<const float4*>(epsg)[(size_t)row * 64 + lane];
      float z0 = mu.x + ev.x * expf(0.5f * lv.x);
      float z1 = mu.y + ev.y * expf(0.5f * lv.y);
      float z2 = mu.z + ev.z * expf(0.5f * lv.z);
      float z3 = mu.w + ev.w * expf(0.5f * lv.w);
      float s2 = wred(z0*z0 + z1*z1 + z2*z2 + z3*z3);
      float klp = (1.0f + lv.x - mu.x*mu.x - expf(lv.x))
                + (1.0f + lv.y - mu.y*mu.y - expf(lv.y))
                + (1.0f + lv.z - mu.z*mu.z - expf(lv.z))
                + (1.0f + lv.w - mu.w*mu.w - expf(lv.w));
      float klt = wred(klp);
      float inv = 1.0f / fmaxf(sqrtf(s2), 1e-12f);
      float4 zv = make_float4(z0*inv, z1*inv, z2*inv, z3*inv);
      reinterpret_cast<float4*>(z)[(size_t)row * 64 + lane] = zv;
      ushort4 o; o.x=f2b(zv.x); o.y=f2b(zv.y); o.z=f2b(zv.z); o.w=f2b(zv.w);
      reinterpret_cast<ushort4*>(zb)[(size_t)row * 64 + lane] = o;
      if (lane == 0) atomicAdd(scal + (row >= 256 ? 1 : 0), -0.5f * klt);
    }
  }
  grid.sync();

  // ================= stage 6: sc GEMM1 [512,256]@[256,512], ks=4 =================
  {
    ushort* LS = reinterpret_cast<ushort*>(SMRAW);
    const int n0 = (bid & 7) * 64, m = (bid >> 3) & 7, ks = bid >> 6;
    gemm_stage<64,64,512,256>(zb, wt+WT_SW1I, wt+WT_SW1T, P, LS, t, n0, m*64, ks*64, ks);
  }
  grid.sync();

  // ================= stage 7: LN2 (512-wide, 4 partials) =================
  {
    LNSM* sm = reinterpret_cast<LNSM*>(SMRAW);
#pragma unroll
    for (int rr = 0; rr < 2; rr++){
      const int row = bid + rr * 256;
      __syncthreads();
      ln_row<512,4>(P, row, row >= 256 ? p.sb1t : p.sb1i,
                    row >= 256 ? p.sgt : p.sgi,
                    row >= 256 ? p.sbet : p.sbei, hb, sm, t);
    }
  }
  grid.sync();

  // ================= stage 8: sc GEMM2 [512,512]@[512,256], ks=8 =================
  {
    ushort* LS = reinterpret_cast<ushort*>(SMRAW);
    const int n0 = (bid & 3) * 64, m = (bid >> 2) & 7, ks = bid >> 5;
    gemm_stage<64,64,256,512>(hb, wt+WT_SW2I, wt+WT_SW2T, P, LS, t, n0, m*64, ks*64, ks);
  }
  grid.sync();

  // ================= stage 9: score partial-sum (8) + bias; ysy =================
  {
    const int wv = t >> 6, lane = t & 63;
    if (wv < 2){
      const int row = bid + wv * 256;
      const float* b2 = row >= 256 ? p.sb2t : p.sb2i;
      const float4* P4 = reinterpret_cast<const float4*>(P);
      float4 v = make_float4(0,0,0,0);
#pragma unroll
      for (int s = 0; s < 8; s++){
        float4 q = P4[((size_t)s * 512 + row) * (Kk/4) + lane];
        v.x += q.x; v.y += q.y; v.z += q.z; v.w += q.w;
      }
      float4 bb = reinterpret_cast<const float4*>(b2)[lane];
      v.x += bb.x; v.y += bb.y; v.z += bb.z; v.w += bb.w;
      reinterpret_cast<float4*>(score)[(size_t)row * 64 + lane] = v;
      float4 zv = reinterpret_cast<const float4*>(z)[(size_t)row * 64 + lane];
      float yp = wred(zv.x*v.x + zv.y*v.y + zv.z*v.z + zv.w*v.w);
      if (lane == 0) ysy[row] = yp;
    }
  }
  grid.sync();

  // ================= stage 10: pairwise dist + histogram =================
  {
    DistSM* sm = reinterpret_cast<DistSM*>(SMRAW);
    const int i = bid, j = t;
    sm->xsh[j] = z[(size_t)i * Kk + j];
#pragma unroll
    for (int k = j; k < 8192; k += 256) sm->hl[k] = 0;
    __syncthreads();
    const float4* y4 = reinterpret_cast<const float4*>(z + (size_t)Bb * Kk);
    const float4* x4 = reinterpret_cast<const float4*>(sm->xsh);
    float acc = 0.0f;
#pragma unroll 4
    for (int d = 0; d < Kk; d += 4){
      float4 xv = x4[d >> 2];
      float4 yv = y4[j * (Kk/4) + (d >> 2)];
      float d0 = xv.x - yv.x, d1 = xv.y - yv.y, d2 = xv.z - yv.z, d3 = xv.w - yv.w;
      acc += d0*d0 + d1*d1 + d2*d2 + d3*d3;
    }
    dist[i * 256 + j] = acc;
    int bin = (int)(acc * 2048.0f);
    bin = bin < 0 ? 0 : (bin > 8191 ? 8191 : bin);
    atomicAdd(&sm->hl[bin], 1);
    __syncthreads();
    for (int k = j; k < 8192; k += 256){
      int c = sm->hl[k];
      if (c) atomicAdd(ghist + k, c);
    }
  }
  grid.sync();

  // ================= stage 11: bw (per-block) + score reduction =================
  {
    ScoreSM* sm = reinterpret_cast<ScoreSM*>(SMRAW);
    const int i = bid, j = t;
    sm->xsh[j]  = z[(size_t)i * Kk + j];
    sm->sxsh[j] = score[(size_t)i * Kk + j];
    {
      const int lane = j & 63, w = j >> 6;
      const int base = j * 32;
      int s = 0;
#pragma unroll
      for (int u = 0; u < 32; u++) s += ghist[base + u];
      int sc = s;
#pragma unroll
      for (int m = 1; m < 64; m <<= 1){
        int o = __shfl_up(sc, m, 64);
        if (lane >= m) sc += o;
      }
      if (lane == 63) sm->wt4[w] = sc;
      __syncthreads();
      int off = 0;
      for (int q = 0; q < w; q++) off += sm->wt4[q];
      int cum = sc + off, basex = cum - s;
#pragma unroll
      for (int rr = 0; rr < 2; rr++){
        int rank = 32768 + rr;
        if (basex < rank && cum >= rank){
          int c = basex;
          for (int u = 0; u < 32; u++){
            c += ghist[base + u];
            if (c >= rank){ sm->bres[rr] = base + u; break; }
          }
        }
      }
      __syncthreads();
      if (j == 0){
        float med = 0.5f * ((sm->bres[0] + 0.5f) + (sm->bres[1] + 0.5f)) * (1.0f / 2048.0f);
        float bw = sqrtf(med * 0.5f);
        bw = fminf(fmaxf(bw, 0.1f), 10.0f);
        sm->bw2 = bw * bw;
      }
      __syncthreads();
    }
    const float bw2 = sm->bw2;
    const float4* sy4 = reinterpret_cast<const float4*>(score + (size_t)Bb * Kk);
    const float4* x4  = reinterpret_cast<const float4*>(sm->xsh);
    const float4* sx4 = reinterpret_cast<const float4*>(sm->sxsh);
    float ssy = 0, xsy = 0;
#pragma unroll 4
    for (int d = 0; d < Kk; d += 4){
      float4 xv  = x4[d >> 2];
      float4 sxv = sx4[d >> 2];
      float4 syv = sy4[j * (Kk/4) + (d >> 2)];
      ssy += sxv.x*syv.x + sxv.y*syv.y + sxv.z*syv.z + sxv.w*syv.w;
      xsy += xv.x*syv.x + xv.y*syv.y + xv.z*syv.z + xv.w*syv.w;
    }
    float d2 = dist[i * 256 + j];
    float kv = expf(-d2 / (2.0f * bw2));
    float t1 = kv * ssy;
    float t2 = (xsy - ysy[Bb + j]) * kv / bw2;
    float t3 = d2 * kv / (bw2 * bw2) - kv * (float)Kk / bw2;
    float s = wred(t1 + t2 + t3);
    if (!(j & 63)) sm->red4[j >> 6] = s;
    __syncthreads();
    if (j == 0) atomicAdd(scal + 2, sm->red4[0] + sm->red4[1] + sm->red4[2] + sm->red4[3]);
  }
  grid.sync();

  // ================= stage 12: finalize =================
  if (bid == 0 && t == 0){
    p.out[0] = 0.5f * (scal[0] + scal[1]) * (1.0f/256.0f)
             + 0.1f * scal[2] * (1.0f/65536.0f);
  }
}

extern "C" void kernel_launch(void* const* d_in, const int* in_sizes, int n_in,
                              void* d_out, int out_size, void* d_ws, size_t ws_size,
                              hipStream_t stream) {
  (void)in_sizes; (void)n_in; (void)out_size; (void)ws_size;
  Params prm;
  prm.img  = (const float*)d_in[0];
  prm.txt  = (const float*)d_in[1];
  prm.epsi = (const float*)d_in[2];
  prm.epst = (const float*)d_in[3];
  prm.mask = (const int*)d_in[4];
  prm.eW1i = (const float*)d_in[5];   prm.eb1i = (const float*)d_in[6];
  prm.egi  = (const float*)d_in[7];   prm.ebei = (const float*)d_in[8];
  prm.eW2i = (const float*)d_in[9];   prm.eb2i = (const float*)d_in[10];
  prm.eW1t = (const float*)d_in[11];  prm.eb1t = (const float*)d_in[12];
  prm.egt  = (const float*)d_in[13];  prm.ebet = (const float*)d_in[14];
  prm.eW2t = (const float*)d_in[15];  prm.eb2t = (const float*)d_in[16];
  prm.sW1i = (const float*)d_in[17];  prm.sb1i = (const float*)d_in[18];
  prm.sgi  = (const float*)d_in[19];  prm.sbei = (const float*)d_in[20];
  prm.sW2i = (const float*)d_in[21];  prm.sb2i = (const float*)d_in[22];
  prm.sW1t = (const float*)d_in[23];  prm.sb1t = (const float*)d_in[24];
  prm.sgt  = (const float*)d_in[25];  prm.sbet = (const float*)d_in[26];
  prm.sW2t = (const float*)d_in[27];  prm.sb2t = (const float*)d_in[28];
  prm.ws   = (float*)d_ws;
  prm.out  = (float*)d_out;

  void* kargs[] = { (void*)&prm };
  hipLaunchCooperativeKernel((const void*)k_mega, dim3(256), dim3(256),
                             kargs, 0, stream);
}

// Round 7
// 389.441 us; speedup vs baseline: 1.0100x; 1.0065x over previous
//
#include <hip/hip_runtime.h>
#include <hip/hip_cooperative_groups.h>
#include <math.h>

namespace cg = cooperative_groups;

#define Bb   256
#define Lq   128
#define D1   768
#define Hh   1024
#define Kk   256
#define K2v  512

// ---- ws float offsets ----
#define OFF_EPSG  0                    // 512*256
#define OFF_P     131072               // 2097152 floats (partial arena)
#define OFF_Z     2228224              // 512*256
#define OFF_SCORE 2359296              // 512*256
#define OFF_DIST  2490368              // 65536
#define OFF_HIST  2555904              // 8192 ints
#define OFF_SCAL  2564096              // [0]=kl_i [1]=kl_t [2]=align
#define OFF_YSY   2564104              // 512
#define OFF_SEQL  2564616              // 256 ints
#define OFF_BF    2564880              // ushort arena (16B aligned)

// ---- ushort offsets inside bf arena ----
#define UB_XG   0                      // 512*768
#define UB_HACT 393216                 // 512*1024 (reused 512*512)
#define UB_ZB   917504                 // 512*256
#define UB_WT   1048576                // transposed bf16 weights
#define WT_EW1I 0
#define WT_EW1T 786432
#define WT_EW2I 1572864
#define WT_EW2T 2097152
#define WT_SW1I 2621440
#define WT_SW1T 2752512
#define WT_SW2I 2883584
#define WT_SW2T 3014656

typedef __attribute__((ext_vector_type(8))) short short8v;
typedef __attribute__((ext_vector_type(4))) float f32x4;

__device__ __forceinline__ float wred(float v){
#pragma unroll
  for (int m = 32; m; m >>= 1) v += __shfl_xor(v, m, 64);
  return v;
}
__device__ __forceinline__ int wredi(int v){
#pragma unroll
  for (int m = 32; m; m >>= 1) v += __shfl_xor(v, m, 64);
  return v;
}
__device__ __forceinline__ float gelu_exact(float x){
  return 0.5f * x * (1.0f + erff(x * 0.70710678118654752f));
}
__device__ __forceinline__ ushort f2b(float f){
  union { float f; unsigned u; } v; v.f = f;
  return (ushort)((v.u + 0x7FFFu + ((v.u >> 16) & 1u)) >> 16);
}

struct Params {
  const float *img, *txt, *epsi, *epst;
  const int   *mask;
  const float *eW1i,*eb1i,*egi,*ebei,*eW2i,*eb2i;
  const float *eW1t,*eb1t,*egt,*ebet,*eW2t,*eb2t;
  const float *sW1i,*sb1i,*sgi,*sbei,*sW2i,*sb2i;
  const float *sW1t,*sb1t,*sgt,*sbet,*sW2t,*sb2t;
  float *ws;
  float *out;
};

// shared-memory overlays
struct ConvSM  { float lsf[32][33]; };
struct DistSM  { float xsh[256]; int hl[8192]; };
struct ScoreSM { float xsh[256]; float sxsh[256]; int wt4[4]; int bres[2]; float red4[4]; float bw2; };
struct LNSM    { float2 wsum[4]; };

// ---- MFMA bf16 GEMM stage (K-split partials into P) ----
template<int BM,int KCH,int N,int K>
__device__ __forceinline__ void gemm_stage(
    const ushort* __restrict__ A, const ushort* __restrict__ WTi,
    const ushort* __restrict__ WTt, float* __restrict__ P,
    ushort* LS, int tid, int n0, int r0, int kb, int ks)
{
  constexpr int RPW = BM / 64;
  const int lane = tid & 63, wid = tid >> 6;
  const ushort* WT = (r0 >= 256) ? WTt : WTi;

  f32x4 acc[RPW][4];
#pragma unroll
  for (int s = 0; s < RPW; s++)
#pragma unroll
    for (int c = 0; c < 4; c++) acc[s][c] = (f32x4){0.f,0.f,0.f,0.f};

  const int l15 = lane & 15, kg = lane >> 4;
  const int rdswz = (kg * 16) ^ ((l15 & 3) << 4);

  for (int k0 = kb; k0 < kb + KCH; k0 += 32){
    __syncthreads();
    constexpr int NCHK = (BM + 64) * 4;
#pragma unroll
    for (int i = 0; i < NCHK / 256; i++){
      const int q = (i * 256 + tid) * 16;
      const int row = q >> 6, koff = q & 63;
      const ushort* src = (row < BM)
          ? (A  + (size_t)(r0 + row) * K + k0)
          : (WT + (size_t)(n0 + row - BM) * K + k0);
      short8v v = *reinterpret_cast<const short8v*>(
          reinterpret_cast<const char*>(src) + koff);
      const int dq = (q & ~63) | (koff ^ ((row & 3) << 4));
      *reinterpret_cast<short8v*>(reinterpret_cast<char*>(LS) + dq) = v;
    }
    __syncthreads();
    const char* Ab  = reinterpret_cast<const char*>(LS);
    const char* Bbp = reinterpret_cast<const char*>(LS + BM * 32);
    short8v ar[RPW], bc[4];
#pragma unroll
    for (int s = 0; s < RPW; s++){
      const int row = wid * (RPW * 16) + s * 16 + l15;
      ar[s] = *reinterpret_cast<const short8v*>(Ab + row * 64 + rdswz);
    }
#pragma unroll
    for (int c = 0; c < 4; c++){
      const int col = c * 16 + l15;
      bc[c] = *reinterpret_cast<const short8v*>(Bbp + col * 64 + rdswz);
    }
#pragma unroll
    for (int s = 0; s < RPW; s++)
#pragma unroll
      for (int c = 0; c < 4; c++)
        acc[s][c] = __builtin_amdgcn_mfma_f32_16x16x32_bf16(ar[s], bc[c], acc[s][c], 0, 0, 0);
  }
#pragma unroll
  for (int s = 0; s < RPW; s++)
#pragma unroll
    for (int c = 0; c < 4; c++)
#pragma unroll
      for (int r = 0; r < 4; r++){
        const int row = r0 + wid * (RPW * 16) + s * 16 + kg * 4 + r;
        const int col = n0 + c * 16 + l15;
        P[((size_t)ks * 512 + row) * N + col] = acc[s][c][r];
      }
}

// ---- LN+gelu over W-wide row, summing NS partials + bias -> bf16 ----
template<int W, int NS>
__device__ __forceinline__ void ln_row(
    const float* __restrict__ P, int row,
    const float* __restrict__ b1, const float* __restrict__ g,
    const float* __restrict__ be, ushort* __restrict__ hb,
    LNSM* sm, int t)
{
  // W/4 float4 per row; threads t < W/4 active
  float4 v = make_float4(0,0,0,0);
  if (t < W/4){
    const float4* P4 = reinterpret_cast<const float4*>(P);
#pragma unroll
    for (int s = 0; s < NS; s++){
      float4 p = P4[((size_t)s * 512 + row) * (W/4) + t];
      v.x += p.x; v.y += p.y; v.z += p.z; v.w += p.w;
    }
    float4 bb = reinterpret_cast<const float4*>(b1)[t];
    v.x += bb.x; v.y += bb.y; v.z += bb.z; v.w += bb.w;
  }
  float ps = wred(v.x + v.y + v.z + v.w);
  float pq = wred(v.x*v.x + v.y*v.y + v.z*v.z + v.w*v.w);
  if (!(t & 63)) sm->wsum[t >> 6] = make_float2(ps, pq);
  __syncthreads();
  float S = 0, Q = 0;
#pragma unroll
  for (int i = 0; i < (W == 1024 ? 4 : 2); i++){ S += sm->wsum[i].x; Q += sm->wsum[i].y; }
  if (t < W/4){
    float mean = S * (1.0f/W);
    float rstd = rsqrtf(Q * (1.0f/W) - mean*mean + 1e-5f);
    float4 gv  = reinterpret_cast<const float4*>(g)[t];
    float4 bev = reinterpret_cast<const float4*>(be)[t];
    ushort4 o;
    o.x = f2b(gelu_exact((v.x - mean)*rstd*gv.x + bev.x));
    o.y = f2b(gelu_exact((v.y - mean)*rstd*gv.y + bev.y));
    o.z = f2b(gelu_exact((v.z - mean)*rstd*gv.z + bev.z));
    o.w = f2b(gelu_exact((v.w - mean)*rstd*gv.w + bev.w));
    reinterpret_cast<ushort4*>(hb)[(size_t)row * (W/4) + t] = o;
  }
}

__global__ __launch_bounds__(256) void k_mega(Params p)
{
  __shared__ __align__(16) char SMRAW[sizeof(DistSM)];
  __shared__ int s_last;
  cg::grid_group grid = cg::this_grid();

  const int bid = blockIdx.x;          // 0..255
  const int t   = threadIdx.x;         // 0..255

  float*  ws    = p.ws;
  float*  epsg  = ws + OFF_EPSG;
  float*  P     = ws + OFF_P;
  float*  z     = ws + OFF_Z;
  float*  score = ws + OFF_SCORE;
  float*  dist  = ws + OFF_DIST;
  int*    ghist = (int*)(ws + OFF_HIST);
  float*  scal  = ws + OFF_SCAL;
  float*  ysy   = ws + OFF_YSY;
  int*    seql  = (int*)(ws + OFF_SEQL);
  ushort* ub    = (ushort*)(ws + OFF_BF);
  ushort* xgb   = ub + UB_XG;
  ushort* hb    = ub + UB_HACT;
  ushort* zb    = ub + UB_ZB;
  ushort* wt    = ub + UB_WT;

  // ================= stage 1: prep (seql, zero, gather) + weight conv =================
  {
    // seq_last for row bid
    int s = 0;
    if (t < 32){
      int4 v = reinterpret_cast<const int4*>(p.mask + bid * Lq)[t];
      s = v.x + v.y + v.z + v.w;
    }
    if (t < 64){
      int tot = wredi(s);
      if (t == 0){ seql[bid] = tot - 1; s_last = tot - 1; }
    }
    // zero hist / scal
    if (t < 8) reinterpret_cast<int4*>(ghist)[bid * 8 + t] = make_int4(0,0,0,0);
    if (bid == 0 && t < 8) scal[t] = 0.0f;
    __syncthreads();
    const int last = s_last;
    // gather + convert x rows
    if (t < 192){
      float4 v = reinterpret_cast<const float4*>(p.img + (size_t)(bid*Lq+last)*D1)[t];
      ushort4 o; o.x=f2b(v.x); o.y=f2b(v.y); o.z=f2b(v.z); o.w=f2b(v.w);
      reinterpret_cast<ushort4*>(xgb + (size_t)bid*D1)[t] = o;
      float4 w = reinterpret_cast<const float4*>(p.txt + (size_t)(bid*Lq+last)*D1)[t];
      ushort4 q; q.x=f2b(w.x); q.y=f2b(w.y); q.z=f2b(w.z); q.w=f2b(w.w);
      reinterpret_cast<ushort4*>(xgb + (size_t)(Bb+bid)*D1)[t] = q;
    }
    if (t < 64){
      reinterpret_cast<float4*>(epsg + (size_t)bid*Kk)[t] =
        reinterpret_cast<const float4*>(p.epsi + (size_t)(bid*Lq+last)*Kk)[t];
      reinterpret_cast<float4*>(epsg + (size_t)(Bb+bid)*Kk)[t] =
        reinterpret_cast<const float4*>(p.epst + (size_t)(bid*Lq+last)*Kk)[t];
    }
    // weight transpose-convert: 3072 tiles, 12 per block
    ConvSM* cs = reinterpret_cast<ConvSM*>(SMRAW);
    for (int it = 0; it < 12; ++it){
      const int wb = bid + it * 256;
      const float* src; ushort* dst; int Kd, Nd, ti;
      if      (wb < 768){  src=p.eW1i; dst=wt+WT_EW1I; Kd=768;  Nd=1024; ti=wb; }
      else if (wb < 1536){ src=p.eW1t; dst=wt+WT_EW1T; Kd=768;  Nd=1024; ti=wb-768; }
      else if (wb < 2048){ src=p.eW2i; dst=wt+WT_EW2I; Kd=1024; Nd=512;  ti=wb-1536; }
      else if (wb < 2560){ src=p.eW2t; dst=wt+WT_EW2T; Kd=1024; Nd=512;  ti=wb-2048; }
      else if (wb < 2688){ src=p.sW1i; dst=wt+WT_SW1I; Kd=256;  Nd=512;  ti=wb-2560; }
      else if (wb < 2816){ src=p.sW1t; dst=wt+WT_SW1T; Kd=256;  Nd=512;  ti=wb-2688; }
      else if (wb < 2944){ src=p.sW2i; dst=wt+WT_SW2I; Kd=512;  Nd=256;  ti=wb-2816; }
      else               { src=p.sW2t; dst=wt+WT_SW2T; Kd=512;  Nd=256;  ti=wb-2944; }
      const int ntile = Nd / 32;
      const int k0 = (ti / ntile) * 32, n0 = (ti % ntile) * 32;
      const int r = t >> 3, q = t & 7;
      float4 v = reinterpret_cast<const float4*>(src + (size_t)(k0+r)*Nd + n0)[q];
      __syncthreads();
      cs->lsf[r][q*4+0]=v.x; cs->lsf[r][q*4+1]=v.y; cs->lsf[r][q*4+2]=v.z; cs->lsf[r][q*4+3]=v.w;
      __syncthreads();
      ushort4 o;
      o.x = f2b(cs->lsf[q*4+0][r]); o.y = f2b(cs->lsf[q*4+1][r]);
      o.z = f2b(cs->lsf[q*4+2][r]); o.w = f2b(cs->lsf[q*4+3][r]);
      *reinterpret_cast<ushort4*>(dst + (size_t)(n0+r)*Kd + k0 + q*4) = o;
    }
  }
  grid.sync();

  // ================= stage 2: enc GEMM1 [512,768]@[768,1024], ks=4 =================
  {
    ushort* LS = reinterpret_cast<ushort*>(SMRAW);
    const int n0 = (bid & 15) * 64, m = (bid >> 4) & 3, ks = bid >> 6;
    gemm_stage<128,192,1024,768>(xgb, wt+WT_EW1I, wt+WT_EW1T, P, LS, t, n0, m*128, ks*192, ks);
  }
  grid.sync();

  // ================= stage 3: LN1 (1024-wide, 4 partials) =================
  {
    LNSM* sm = reinterpret_cast<LNSM*>(SMRAW);
#pragma unroll
    for (int rr = 0; rr < 2; rr++){
      const int row = bid + rr * 256;
      __syncthreads();
      ln_row<1024,4>(P, row, row >= 256 ? p.eb1t : p.eb1i,
                     row >= 256 ? p.egt : p.egi,
                     row >= 256 ? p.ebet : p.ebei, hb, sm, t);
    }
  }
  grid.sync();

  // ================= stage 4: enc GEMM2 [512,1024]@[1024,512], ks=8 =================
  {
    ushort* LS = reinterpret_cast<ushort*>(SMRAW);
    const int n0 = (bid & 7) * 64, m = (bid >> 3) & 3, ks = bid >> 5;
    gemm_stage<128,128,512,1024>(hb, wt+WT_EW2I, wt+WT_EW2T, P, LS, t, n0, m*128, ks*128, ks);
  }
  grid.sync();

  // ================= stage 5: reparam + normalize + KL (8 partials) =================
  {
    const int wv = t >> 6, lane = t & 63;
    if (wv < 2 && lane < 64){
      const int row = bid + wv * 256;
      const float* b2 = row >= 256 ? p.eb2t : p.eb2i;
      const float4* P4 = reinterpret_cast<const float4*>(P);
      float4 mu = make_float4(0,0,0,0), lv = make_float4(0,0,0,0);
#pragma unroll
      for (int s = 0; s < 8; s++){
        float4 a = P4[((size_t)s * 512 + row) * (K2v/4) + lane];
        float4 c = P4[((size_t)s * 512 + row) * (K2v/4) + 64 + lane];
        mu.x += a.x; mu.y += a.y; mu.z += a.z; mu.w += a.w;
        lv.x += c.x; lv.y += c.y; lv.z += c.z; lv.w += c.w;
      }
      float4 bm = reinterpret_cast<const float4*>(b2)[lane];
      float4 bl = reinterpret_cast<const float4*>(b2)[64 + lane];
      mu.x += bm.x; mu.y += bm.y; mu.z += bm.z; mu.w += bm.w;
      lv.x += bl.x; lv.y += bl.y; lv.z += bl.z; lv.w += bl.w;
      float4 ev = reinterpret_cast<const float4*>(epsg)[(size_t)row * 64 + lane];
      float z0 = mu.x + ev.x * expf(0.5f * lv.x);
      float z1 = mu.y + ev.y * expf(0.5f * lv.y);
      float z2 = mu.z + ev.z * expf(0.5f * lv.z);
      float z3 = mu.w + ev.w * expf(0.5f * lv.w);
      float s2 = wred(z0*z0 + z1*z1 + z2*z2 + z3*z3);
      float klp = (1.0f + lv.x - mu.x*mu.x - expf(lv.x))
                + (1.0f + lv.y - mu.y*mu.y - expf(lv.y))
                + (1.0f + lv.z - mu.z*mu.z - expf(lv.z))
                + (1.0f + lv.w - mu.w*mu.w - expf(lv.w));
      float klt = wred(klp);
      float inv = 1.0f / fmaxf(sqrtf(s2), 1e-12f);
      float4 zv = make_float4(z0*inv, z1*inv, z2*inv, z3*inv);
      reinterpret_cast<float4*>(z)[(size_t)row * 64 + lane] = zv;
      ushort4 o; o.x=f2b(zv.x); o.y=f2b(zv.y); o.z=f2b(zv.z); o.w=f2b(zv.w);
      reinterpret_cast<ushort4*>(zb)[(size_t)row * 64 + lane] = o;
      if (lane == 0) atomicAdd(scal + (row >= 256 ? 1 : 0), -0.5f * klt);
    }
  }
  grid.sync();

  // ================= stage 6: sc GEMM1 [512,256]@[256,512], ks=4 =================
  {
    ushort* LS = reinterpret_cast<ushort*>(SMRAW);
    const int n0 = (bid & 7) * 64, m = (bid >> 3) & 7, ks = bid >> 6;
    gemm_stage<64,64,512,256>(zb, wt+WT_SW1I, wt+WT_SW1T, P, LS, t, n0, m*64, ks*64, ks);
  }
  grid.sync();

  // ================= stage 7: LN2 (512-wide, 4 partials) =================
  {
    LNSM* sm = reinterpret_cast<LNSM*>(SMRAW);
#pragma unroll
    for (int rr = 0; rr < 2; rr++){
      const int row = bid + rr * 256;
      __syncthreads();
      ln_row<512,4>(P, row, row >= 256 ? p.sb1t : p.sb1i,
                    row >= 256 ? p.sgt : p.sgi,
                    row >= 256 ? p.sbet : p.sbei, hb, sm, t);
    }
  }
  grid.sync();

  // ================= stage 8: sc GEMM2 [512,512]@[512,256], ks=8 =================
  {
    ushort* LS = reinterpret_cast<ushort*>(SMRAW);
    const int n0 = (bid & 3) * 64, m = (bid >> 2) & 7, ks = bid >> 5;
    gemm_stage<64,64,256,512>(hb, wt+WT_SW2I, wt+WT_SW2T, P, LS, t, n0, m*64, ks*64, ks);
  }
  grid.sync();

  // ================= stage 9: score partial-sum (8) + bias; ysy =================
  {
    const int wv = t >> 6, lane = t & 63;
    if (wv < 2){
      const int row = bid + wv * 256;
      const float* b2 = row >= 256 ? p.sb2t : p.sb2i;
      const float4* P4 = reinterpret_cast<const float4*>(P);
      float4 v = make_float4(0,0,0,0);
#pragma unroll
      for (int s = 0; s < 8; s++){
        float4 q = P4[((size_t)s * 512 + row) * (Kk/4) + lane];
        v.x += q.x; v.y += q.y; v.z += q.z; v.w += q.w;
      }
      float4 bb = reinterpret_cast<const float4*>(b2)[lane];
      v.x += bb.x; v.y += bb.y; v.z += bb.z; v.w += bb.w;
      reinterpret_cast<float4*>(score)[(size_t)row * 64 + lane] = v;
      float4 zv = reinterpret_cast<const float4*>(z)[(size_t)row * 64 + lane];
      float yp = wred(zv.x*v.x + zv.y*v.y + zv.z*v.z + zv.w*v.w);
      if (lane == 0) ysy[row] = yp;
    }
  }
  grid.sync();

  // ================= stage 10: pairwise dist + histogram =================
  {
    DistSM* sm = reinterpret_cast<DistSM*>(SMRAW);
    const int i = bid, j = t;
    sm->xsh[j] = z[(size_t)i * Kk + j];
#pragma unroll
    for (int k = j; k < 8192; k += 256) sm->hl[k] = 0;
    __syncthreads();
    const float4* y4 = reinterpret_cast<const float4*>(z + (size_t)Bb * Kk);
    const float4* x4 = reinterpret_cast<const float4*>(sm->xsh);
    float acc = 0.0f;
#pragma unroll 4
    for (int d = 0; d < Kk; d += 4){
      float4 xv = x4[d >> 2];
      float4 yv = y4[j * (Kk/4) + (d >> 2)];
      float d0 = xv.x - yv.x, d1 = xv.y - yv.y, d2 = xv.z - yv.z, d3 = xv.w - yv.w;
      acc += d0*d0 + d1*d1 + d2*d2 + d3*d3;
    }
    dist[i * 256 + j] = acc;
    int bin = (int)(acc * 2048.0f);
    bin = bin < 0 ? 0 : (bin > 8191 ? 8191 : bin);
    atomicAdd(&sm->hl[bin], 1);
    __syncthreads();
    for (int k = j; k < 8192; k += 256){
      int c = sm->hl[k];
      if (c) atomicAdd(ghist + k, c);
    }
  }
  grid.sync();

  // ================= stage 11: bw (per-block) + score reduction =================
  {
    ScoreSM* sm = reinterpret_cast<ScoreSM*>(SMRAW);
    const int i = bid, j = t;
    sm->xsh[j]  = z[(size_t)i * Kk + j];
    sm->sxsh[j] = score[(size_t)i * Kk + j];
    {
      const int lane = j & 63, w = j >> 6;
      const int base = j * 32;
      int s = 0;
#pragma unroll
      for (int u = 0; u < 32; u++) s += ghist[base + u];
      int sc = s;
#pragma unroll
      for (int m = 1; m < 64; m <<= 1){
        int o = __shfl_up(sc, m, 64);
        if (lane >= m) sc += o;
      }
      if (lane == 63) sm->wt4[w] = sc;
      __syncthreads();
      int off = 0;
      for (int q = 0; q < w; q++) off += sm->wt4[q];
      int cum = sc + off, basex = cum - s;
#pragma unroll
      for (int rr = 0; rr < 2; rr++){
        int rank = 32768 + rr;
        if (basex < rank && cum >= rank){
          int c = basex;
          for (int u = 0; u < 32; u++){
            c += ghist[base + u];
            if (c >= rank){ sm->bres[rr] = base + u; break; }
          }
        }
      }
      __syncthreads();
      if (j == 0){
        float med = 0.5f * ((sm->bres[0] + 0.5f) + (sm->bres[1] + 0.5f)) * (1.0f / 2048.0f);
        float bw = sqrtf(med * 0.5f);
        bw = fminf(fmaxf(bw, 0.1f), 10.0f);
        sm->bw2 = bw * bw;
      }
      __syncthreads();
    }
    const float bw2 = sm->bw2;
    const float4* sy4 = reinterpret_cast<const float4*>(score + (size_t)Bb * Kk);
    const float4* x4  = reinterpret_cast<const float4*>(sm->xsh);
    const float4* sx4 = reinterpret_cast<const float4*>(sm->sxsh);
    float ssy = 0, xsy = 0;
#pragma unroll 4
    for (int d = 0; d < Kk; d += 4){
      float4 xv  = x4[d >> 2];
      float4 sxv = sx4[d >> 2];
      float4 syv = sy4[j * (Kk/4) + (d >> 2)];
      ssy += sxv.x*syv.x + sxv.y*syv.y + sxv.z*syv.z + sxv.w*syv.w;
      xsy += xv.x*syv.x + xv.y*syv.y + xv.z*syv.z + xv.w*syv.w;
    }
    float d2 = dist[i * 256 + j];
    float kv = expf(-d2 / (2.0f * bw2));
    float t1 = kv * ssy;
    float t2 = (xsy - ysy[Bb + j]) * kv / bw2;
    float t3 = d2 * kv / (bw2 * bw2) - kv * (float)Kk / bw2;
    float s = wred(t1 + t2 + t3);
    if (!(j & 63)) sm->red4[j >> 6] = s;
    __syncthreads();
    if (j == 0) atomicAdd(scal + 2, sm->red4[0] + sm->red4[1] + sm->red4[2] + sm->red4[3]);
  }
  grid.sync();

  // ================= stage 12: finalize =================
  if (bid == 0 && t == 0){
    p.out[0] = 0.5f * (scal[0] + scal[1]) * (1.0f/256.0f)
             + 0.1f * scal[2] * (1.0f/65536.0f);
  }
}

extern "C" void kernel_launch(void* const* d_in, const int* in_sizes, int n_in,
                              void* d_out, int out_size, void* d_ws, size_t ws_size,
                              hipStream_t stream) {
  (void)in_sizes; (void)n_in; (void)out_size; (void)ws_size;
  Params prm;
  prm.img  = (const float*)d_in[0];
  prm.txt  = (const float*)d_in[1];
  prm.epsi = (const float*)d_in[2];
  prm.epst = (const float*)d_in[3];
  prm.mask = (const int*)d_in[4];
  prm.eW1i = (const float*)d_in[5];   prm.eb1i = (const float*)d_in[6];
  prm.egi  = (const float*)d_in[7];   prm.ebei = (const float*)d_in[8];
  prm.eW2i = (const float*)d_in[9];   prm.eb2i = (const float*)d_in[10];
  prm.eW1t = (const float*)d_in[11];  prm.eb1t = (const float*)d_in[12];
  prm.egt  = (const float*)d_in[13];  prm.ebet = (const float*)d_in[14];
  prm.eW2t = (const float*)d_in[15];  prm.eb2t = (const float*)d_in[16];
  prm.sW1i = (const float*)d_in[17];  prm.sb1i = (const float*)d_in[18];
  prm.sgi  = (const float*)d_in[19];  prm.sbei = (const float*)d_in[20];
  prm.sW2i = (const float*)d_in[21];  prm.sb2i = (const float*)d_in[22];
  prm.sW1t = (const float*)d_in[23];  prm.sb1t = (const float*)d_in[24];
  prm.sgt  = (const float*)d_in[25];  prm.sbet = (const float*)d_in[26];
  prm.sW2t = (const float*)d_in[27];  prm.sb2t = (const float*)d_in[28];
  prm.ws   = (float*)d_ws;
  prm.out  = (float*)d_out;

  void* kargs[] = { (void*)&prm };
  hipLaunchCooperativeKernel((const void*)k_mega, dim3(256), dim3(256),
                             kargs, 0, stream);
}

// Round 8
// 94.476 us; speedup vs baseline: 4.1635x; 4.1221x over previous
//
#include <hip/hip_runtime.h>
#include <math.h>

#define Bb   256
#define Lq   128
#define D1   768
#define Hh   1024
#define Kk   256
#define K2v  512

// ---- ws float offsets ----
#define OFF_EPSG  0                    // 512*256
#define OFF_P     131072               // 4194304 floats (partial arena, max ks=8 N=1024 / ks=16 N=512)
#define OFF_Z     4325376              // 512*256
#define OFF_SCORE 4456448              // 512*256
#define OFF_DIST  4587520              // 65536
#define OFF_HIST  4653056              // 8192 ints
#define OFF_SCAL  4661248              // [0]=kl_i [1]=kl_t [2]=align [3]=bw2 [4]=counter
#define OFF_YSY   4661256              // 512
#define OFF_BF    4661768              // ushort arena (16B aligned)

// ---- ushort offsets inside bf arena ----
#define UB_XG   0                      // 512*768
#define UB_HACT 393216                 // 512*1024 (reused 512*512)
#define UB_ZB   917504                 // 512*256
#define UB_WT   1048576                // transposed bf16 weights
#define WT_EW1I 0
#define WT_EW1T 786432
#define WT_EW2I 1572864
#define WT_EW2T 2097152
#define WT_SW1I 2621440
#define WT_SW1T 2752512
#define WT_SW2I 2883584
#define WT_SW2T 3014656

typedef __attribute__((ext_vector_type(8))) short short8v;
typedef __attribute__((ext_vector_type(4))) float f32x4;

__device__ __forceinline__ float wred(float v){
#pragma unroll
  for (int m = 32; m; m >>= 1) v += __shfl_xor(v, m, 64);
  return v;
}
__device__ __forceinline__ int wredi(int v){
#pragma unroll
  for (int m = 32; m; m >>= 1) v += __shfl_xor(v, m, 64);
  return v;
}
__device__ __forceinline__ float gelu_exact(float x){
  return 0.5f * x * (1.0f + erff(x * 0.70710678118654752f));
}
__device__ __forceinline__ ushort f2b(float f){
  union { float f; unsigned u; } v; v.f = f;
  return (ushort)((v.u + 0x7FFFu + ((v.u >> 16) & 1u)) >> 16);
}

// ---- MFMA bf16 GEMM stage body (K-split partials into P) ----
template<int BM,int KCH,int N,int K>
__device__ __forceinline__ void gemm_stage(
    const ushort* __restrict__ A, const ushort* __restrict__ WTi,
    const ushort* __restrict__ WTt, float* __restrict__ P,
    ushort* LS, int tid, int n0, int r0, int kb, int ks)
{
  constexpr int RPW = BM / 64;
  const int lane = tid & 63, wid = tid >> 6;
  const ushort* WT = (r0 >= 256) ? WTt : WTi;

  f32x4 acc[RPW][4];
#pragma unroll
  for (int s = 0; s < RPW; s++)
#pragma unroll
    for (int c = 0; c < 4; c++) acc[s][c] = (f32x4){0.f,0.f,0.f,0.f};

  const int l15 = lane & 15, kg = lane >> 4;
  const int rdswz = (kg * 16) ^ ((l15 & 3) << 4);

  for (int k0 = kb; k0 < kb + KCH; k0 += 32){
    __syncthreads();
    constexpr int NCHK = (BM + 64) * 4;
#pragma unroll
    for (int i = 0; i < NCHK / 256; i++){
      const int q = (i * 256 + tid) * 16;
      const int row = q >> 6, koff = q & 63;
      const ushort* src = (row < BM)
          ? (A  + (size_t)(r0 + row) * K + k0)
          : (WT + (size_t)(n0 + row - BM) * K + k0);
      short8v v = *reinterpret_cast<const short8v*>(
          reinterpret_cast<const char*>(src) + koff);
      const int dq = (q & ~63) | (koff ^ ((row & 3) << 4));
      *reinterpret_cast<short8v*>(reinterpret_cast<char*>(LS) + dq) = v;
    }
    __syncthreads();
    const char* Ab  = reinterpret_cast<const char*>(LS);
    const char* Bbp = reinterpret_cast<const char*>(LS + BM * 32);
    short8v ar[RPW], bc[4];
#pragma unroll
    for (int s = 0; s < RPW; s++){
      const int row = wid * (RPW * 16) + s * 16 + l15;
      ar[s] = *reinterpret_cast<const short8v*>(Ab + row * 64 + rdswz);
    }
#pragma unroll
    for (int c = 0; c < 4; c++){
      const int col = c * 16 + l15;
      bc[c] = *reinterpret_cast<const short8v*>(Bbp + col * 64 + rdswz);
    }
#pragma unroll
    for (int s = 0; s < RPW; s++)
#pragma unroll
      for (int c = 0; c < 4; c++)
        acc[s][c] = __builtin_amdgcn_mfma_f32_16x16x32_bf16(ar[s], bc[c], acc[s][c], 0, 0, 0);
  }
#pragma unroll
  for (int s = 0; s < RPW; s++)
#pragma unroll
    for (int c = 0; c < 4; c++)
#pragma unroll
      for (int r = 0; r < 4; r++){
        const int row = r0 + wid * (RPW * 16) + s * 16 + kg * 4 + r;
        const int col = n0 + c * 16 + l15;
        P[((size_t)ks * 512 + row) * N + col] = acc[s][c][r];
      }
}

// ---------------- pure GEMM kernel ----------------
template<int BM,int KCH,int N,int K>
__global__ __launch_bounds__(256) void k_mgemm(
    const ushort* __restrict__ A, const ushort* __restrict__ WTi,
    const ushort* __restrict__ WTt, float* __restrict__ P)
{
  __shared__ __align__(16) ushort LS[(BM + 64) * 32];
  gemm_stage<BM,KCH,N,K>(A, WTi, WTt, P, LS, threadIdx.x,
                         blockIdx.x * 64, blockIdx.y * BM,
                         blockIdx.z * KCH, blockIdx.z);
}

// ---------------- prep: zero + seq_last + gather/convert + weight transpose ----------------
__global__ __launch_bounds__(256) void k_prep(
    const float* __restrict__ img, const float* __restrict__ txt,
    const float* __restrict__ epsi, const float* __restrict__ epst,
    const int* __restrict__ mask,
    const float* __restrict__ eW1i, const float* __restrict__ eW1t,
    const float* __restrict__ eW2i, const float* __restrict__ eW2t,
    const float* __restrict__ sW1i, const float* __restrict__ sW1t,
    const float* __restrict__ sW2i, const float* __restrict__ sW2t,
    ushort* __restrict__ xgb, float* __restrict__ epsg, ushort* __restrict__ wt,
    int* __restrict__ ghist, float* __restrict__ scal)
{
  __shared__ float lsf[32][33];
  __shared__ int s_last;
  const int bid = blockIdx.x, t = threadIdx.x;
  if (bid < 256){
    // zero hist/scal
    if (t < 8) reinterpret_cast<int4*>(ghist)[bid * 8 + t] = make_int4(0,0,0,0);
    if (bid == 0 && t < 8) scal[t] = 0.0f;
    // seq_last
    int s = 0;
    if (t < 32){
      int4 v = reinterpret_cast<const int4*>(mask + bid * Lq)[t];
      s = v.x + v.y + v.z + v.w;
    }
    if (t < 64){
      int tot = wredi(s);
      if (t == 0) s_last = tot - 1;
    }
    __syncthreads();
    const int last = s_last;
    if (t < 192){
      float4 v = reinterpret_cast<const float4*>(img + (size_t)(bid*Lq+last)*D1)[t];
      ushort4 o; o.x=f2b(v.x); o.y=f2b(v.y); o.z=f2b(v.z); o.w=f2b(v.w);
      reinterpret_cast<ushort4*>(xgb + (size_t)bid*D1)[t] = o;
      float4 w = reinterpret_cast<const float4*>(txt + (size_t)(bid*Lq+last)*D1)[t];
      ushort4 q; q.x=f2b(w.x); q.y=f2b(w.y); q.z=f2b(w.z); q.w=f2b(w.w);
      reinterpret_cast<ushort4*>(xgb + (size_t)(Bb+bid)*D1)[t] = q;
    }
    if (t < 64){
      reinterpret_cast<float4*>(epsg + (size_t)bid*Kk)[t] =
        reinterpret_cast<const float4*>(epsi + (size_t)(bid*Lq+last)*Kk)[t];
      reinterpret_cast<float4*>(epsg + (size_t)(Bb+bid)*Kk)[t] =
        reinterpret_cast<const float4*>(epst + (size_t)(bid*Lq+last)*Kk)[t];
    }
    return;
  }
  // weight transpose-convert: W[K][N] f32 -> WT[N][K] bf16, 32x32 tiles
  const int wb = bid - 256;
  const float* src; ushort* dst; int Kd, Nd, ti;
  if      (wb < 768){  src=eW1i; dst=wt+WT_EW1I; Kd=768;  Nd=1024; ti=wb; }
  else if (wb < 1536){ src=eW1t; dst=wt+WT_EW1T; Kd=768;  Nd=1024; ti=wb-768; }
  else if (wb < 2048){ src=eW2i; dst=wt+WT_EW2I; Kd=1024; Nd=512;  ti=wb-1536; }
  else if (wb < 2560){ src=eW2t; dst=wt+WT_EW2T; Kd=1024; Nd=512;  ti=wb-2048; }
  else if (wb < 2688){ src=sW1i; dst=wt+WT_SW1I; Kd=256;  Nd=512;  ti=wb-2560; }
  else if (wb < 2816){ src=sW1t; dst=wt+WT_SW1T; Kd=256;  Nd=512;  ti=wb-2688; }
  else if (wb < 2944){ src=sW2i; dst=wt+WT_SW2I; Kd=512;  Nd=256;  ti=wb-2816; }
  else               { src=sW2t; dst=wt+WT_SW2T; Kd=512;  Nd=256;  ti=wb-2944; }
  const int ntile = Nd / 32;
  const int k0 = (ti / ntile) * 32, n0 = (ti % ntile) * 32;
  const int r = t >> 3, q = t & 7;
  float4 v = reinterpret_cast<const float4*>(src + (size_t)(k0+r)*Nd + n0)[q];
  lsf[r][q*4+0]=v.x; lsf[r][q*4+1]=v.y; lsf[r][q*4+2]=v.z; lsf[r][q*4+3]=v.w;
  __syncthreads();
  ushort4 o;
  o.x = f2b(lsf[q*4+0][r]); o.y = f2b(lsf[q*4+1][r]);
  o.z = f2b(lsf[q*4+2][r]); o.w = f2b(lsf[q*4+3][r]);
  *reinterpret_cast<ushort4*>(dst + (size_t)(n0+r)*Kd + k0 + q*4) = o;
}

// ---------------- LN+gelu 1024-wide (sum NS partials + bias) -> bf16 ----------------
template<int NS>
__global__ __launch_bounds__(256) void k_ln1(
    const float* __restrict__ P,
    const float* __restrict__ b1i, const float* __restrict__ b1t,
    const float* __restrict__ gi,  const float* __restrict__ gt,
    const float* __restrict__ bei, const float* __restrict__ bet,
    ushort* __restrict__ hb)
{
  __shared__ float2 wsum[4];
  const int row = blockIdx.x, t = threadIdx.x;
  const float* b1 = row >= 256 ? b1t : b1i;
  const float* g  = row >= 256 ? gt  : gi;
  const float* be = row >= 256 ? bet : bei;
  const float4* P4 = reinterpret_cast<const float4*>(P);
  float4 v = make_float4(0,0,0,0);
#pragma unroll
  for (int s = 0; s < NS; s++){
    float4 p = P4[((size_t)s * 512 + row) * (Hh/4) + t];
    v.x += p.x; v.y += p.y; v.z += p.z; v.w += p.w;
  }
  float4 bb = reinterpret_cast<const float4*>(b1)[t];
  v.x += bb.x; v.y += bb.y; v.z += bb.z; v.w += bb.w;
  float ps = wred(v.x + v.y + v.z + v.w);
  float pq = wred(v.x*v.x + v.y*v.y + v.z*v.z + v.w*v.w);
  if (!(t & 63)) wsum[t >> 6] = make_float2(ps, pq);
  __syncthreads();
  float S = 0, Q = 0;
#pragma unroll
  for (int i = 0; i < 4; i++){ S += wsum[i].x; Q += wsum[i].y; }
  float mean = S * (1.0f/Hh);
  float rstd = rsqrtf(Q * (1.0f/Hh) - mean*mean + 1e-5f);
  float4 gv  = reinterpret_cast<const float4*>(g)[t];
  float4 bev = reinterpret_cast<const float4*>(be)[t];
  ushort4 o;
  o.x = f2b(gelu_exact((v.x - mean)*rstd*gv.x + bev.x));
  o.y = f2b(gelu_exact((v.y - mean)*rstd*gv.y + bev.y));
  o.z = f2b(gelu_exact((v.z - mean)*rstd*gv.z + bev.z));
  o.w = f2b(gelu_exact((v.w - mean)*rstd*gv.w + bev.w));
  reinterpret_cast<ushort4*>(hb)[(size_t)row * 256 + t] = o;
}

// ---------------- LN+gelu 512-wide (sum NS partials + bias) -> bf16 ----------------
template<int NS>
__global__ __launch_bounds__(128) void k_ln2(
    const float* __restrict__ P,
    const float* __restrict__ b1i, const float* __restrict__ b1t,
    const float* __restrict__ gi,  const float* __restrict__ gt,
    const float* __restrict__ bei, const float* __restrict__ bet,
    ushort* __restrict__ hb2)
{
  __shared__ float2 wsum[2];
  const int row = blockIdx.x, t = threadIdx.x;
  const float* b1 = row >= 256 ? b1t : b1i;
  const float* g  = row >= 256 ? gt  : gi;
  const float* be = row >= 256 ? bet : bei;
  const float4* P4 = reinterpret_cast<const float4*>(P);
  float4 v = make_float4(0,0,0,0);
#pragma unroll
  for (int s = 0; s < NS; s++){
    float4 p = P4[((size_t)s * 512 + row) * (K2v/4) + t];
    v.x += p.x; v.y += p.y; v.z += p.z; v.w += p.w;
  }
  float4 bb = reinterpret_cast<const float4*>(b1)[t];
  v.x += bb.x; v.y += bb.y; v.z += bb.z; v.w += bb.w;
  float ps = wred(v.x + v.y + v.z + v.w);
  float pq = wred(v.x*v.x + v.y*v.y + v.z*v.z + v.w*v.w);
  if (!(t & 63)) wsum[t >> 6] = make_float2(ps, pq);
  __syncthreads();
  float S = wsum[0].x + wsum[1].x, Q = wsum[0].y + wsum[1].y;
  float mean = S * (1.0f/K2v);
  float rstd = rsqrtf(Q * (1.0f/K2v) - mean*mean + 1e-5f);
  float4 gv  = reinterpret_cast<const float4*>(g)[t];
  float4 bev = reinterpret_cast<const float4*>(be)[t];
  ushort4 o;
  o.x = f2b(gelu_exact((v.x - mean)*rstd*gv.x + bev.x));
  o.y = f2b(gelu_exact((v.y - mean)*rstd*gv.y + bev.y));
  o.z = f2b(gelu_exact((v.z - mean)*rstd*gv.z + bev.z));
  o.w = f2b(gelu_exact((v.w - mean)*rstd*gv.w + bev.w));
  reinterpret_cast<ushort4*>(hb2)[(size_t)row * 128 + t] = o;
}

// ---------------- reparam + normalize + KL (sum NS partials + bias) ----------------
template<int NS>
__global__ __launch_bounds__(64) void k_reparam(
    const float* __restrict__ P,
    const float* __restrict__ b2i, const float* __restrict__ b2t,
    const float* __restrict__ epsg, float* __restrict__ z,
    ushort* __restrict__ zb, float* __restrict__ kl)
{
  const int row = blockIdx.x, t = threadIdx.x;
  const float* b2 = row >= 256 ? b2t : b2i;
  const float4* P4 = reinterpret_cast<const float4*>(P);
  float4 mu = make_float4(0,0,0,0), lv = make_float4(0,0,0,0);
#pragma unroll
  for (int s = 0; s < NS; s++){
    float4 a = P4[((size_t)s * 512 + row) * (K2v/4) + t];
    float4 c = P4[((size_t)s * 512 + row) * (K2v/4) + 64 + t];
    mu.x += a.x; mu.y += a.y; mu.z += a.z; mu.w += a.w;
    lv.x += c.x; lv.y += c.y; lv.z += c.z; lv.w += c.w;
  }
  float4 bm = reinterpret_cast<const float4*>(b2)[t];
  float4 bl = reinterpret_cast<const float4*>(b2)[64 + t];
  mu.x += bm.x; mu.y += bm.y; mu.z += bm.z; mu.w += bm.w;
  lv.x += bl.x; lv.y += bl.y; lv.z += bl.z; lv.w += bl.w;
  float4 ev = reinterpret_cast<const float4*>(epsg)[(size_t)row * 64 + t];
  float z0 = mu.x + ev.x * expf(0.5f * lv.x);
  float z1 = mu.y + ev.y * expf(0.5f * lv.y);
  float z2 = mu.z + ev.z * expf(0.5f * lv.z);
  float z3 = mu.w + ev.w * expf(0.5f * lv.w);
  float s2 = wred(z0*z0 + z1*z1 + z2*z2 + z3*z3);
  float klp = (1.0f + lv.x - mu.x*mu.x - expf(lv.x))
            + (1.0f + lv.y - mu.y*mu.y - expf(lv.y))
            + (1.0f + lv.z - mu.z*mu.z - expf(lv.z))
            + (1.0f + lv.w - mu.w*mu.w - expf(lv.w));
  float klt = wred(klp);
  float inv = 1.0f / fmaxf(sqrtf(s2), 1e-12f);
  float4 zv = make_float4(z0*inv, z1*inv, z2*inv, z3*inv);
  reinterpret_cast<float4*>(z)[(size_t)row * 64 + t] = zv;
  ushort4 o; o.x=f2b(zv.x); o.y=f2b(zv.y); o.z=f2b(zv.z); o.w=f2b(zv.w);
  reinterpret_cast<ushort4*>(zb)[(size_t)row * 64 + t] = o;
  if (t == 0) atomicAdd(kl + (row >= 256 ? 1 : 0), -0.5f * klt);
}

// ---------------- fused: sc GEMM1 (blocks 0..255) + dist/hist (blocks 256..511) ----------------
__global__ __launch_bounds__(256) void k_sc1dist(
    const ushort* __restrict__ zb, const ushort* __restrict__ WTi,
    const ushort* __restrict__ WTt, float* __restrict__ P,
    const float* __restrict__ z, float* __restrict__ dist, int* __restrict__ ghist)
{
  __shared__ __align__(16) char SM[256*4 + 8192*4];
  const int bid = blockIdx.x, t = threadIdx.x;
  if (bid < 256){
    ushort* LS = reinterpret_cast<ushort*>(SM);
    const int n0 = (bid & 7) * 64;
    const int r0 = ((bid >> 3) & 7) * 64;
    const int ks = bid >> 6;
    gemm_stage<64,64,512,256>(zb, WTi, WTt, P, LS, t, n0, r0, ks * 64, ks);
    return;
  }
  float* xsh = reinterpret_cast<float*>(SM);
  int*   hl  = reinterpret_cast<int*>(SM + 1024);
  const int i = bid - 256, j = t;
  xsh[j] = z[(size_t)i * Kk + j];
#pragma unroll
  for (int k = j; k < 8192; k += 256) hl[k] = 0;
  __syncthreads();
  const float4* y4 = reinterpret_cast<const float4*>(z + (size_t)Bb * Kk);
  const float4* x4 = reinterpret_cast<const float4*>(xsh);
  float acc = 0.0f;
#pragma unroll 4
  for (int d = 0; d < Kk; d += 4){
    float4 xv = x4[d >> 2];
    float4 yv = y4[j * (Kk/4) + (d >> 2)];
    float d0 = xv.x - yv.x, d1 = xv.y - yv.y, d2 = xv.z - yv.z, d3 = xv.w - yv.w;
    acc += d0*d0 + d1*d1 + d2*d2 + d3*d3;
  }
  dist[i * 256 + j] = acc;
  int bin = (int)(acc * 2048.0f);
  bin = bin < 0 ? 0 : (bin > 8191 ? 8191 : bin);
  atomicAdd(&hl[bin], 1);
  __syncthreads();
  for (int k = j; k < 8192; k += 256){
    int c = hl[k];
    if (c) atomicAdd(ghist + k, c);
  }
}

// ---------------- fused: score partial-sum + ysy (blocks 0..127) + bw (block 128) ----------------
template<int NS>
__global__ __launch_bounds__(256) void k_sum2bw(
    const float* __restrict__ P,
    const float* __restrict__ b2i, const float* __restrict__ b2t,
    const float* __restrict__ z, float* __restrict__ score, float* __restrict__ ysy,
    const int* __restrict__ ghist, float* __restrict__ scal)
{
  const int bid = blockIdx.x, t = threadIdx.x;
  if (bid < 128){
    const int row = bid * 4 + (t >> 6), lane = t & 63;
    const float* b2 = row >= 256 ? b2t : b2i;
    const float4* P4 = reinterpret_cast<const float4*>(P);
    float4 v = make_float4(0,0,0,0);
#pragma unroll
    for (int s = 0; s < NS; s++){
      float4 q = P4[((size_t)s * 512 + row) * (Kk/4) + lane];
      v.x += q.x; v.y += q.y; v.z += q.z; v.w += q.w;
    }
    float4 bb = reinterpret_cast<const float4*>(b2)[lane];
    v.x += bb.x; v.y += bb.y; v.z += bb.z; v.w += bb.w;
    reinterpret_cast<float4*>(score)[(size_t)row * 64 + lane] = v;
    float4 zv = reinterpret_cast<const float4*>(z)[(size_t)row * 64 + lane];
    float yp = wred(zv.x*v.x + zv.y*v.y + zv.z*v.z + zv.w*v.w);
    if (lane == 0) ysy[row] = yp;
    return;
  }
  // bw block
  __shared__ int wt4[4];
  __shared__ int bres[2];
  const int lane = t & 63, w = t >> 6;
  const int base = t * 32;
  int s = 0;
#pragma unroll
  for (int u = 0; u < 32; u++) s += ghist[base + u];
  int sc = s;
#pragma unroll
  for (int m = 1; m < 64; m <<= 1){
    int o = __shfl_up(sc, m, 64);
    if (lane >= m) sc += o;
  }
  if (lane == 63) wt4[w] = sc;
  __syncthreads();
  int off = 0;
  for (int q = 0; q < w; q++) off += wt4[q];
  int cum = sc + off, basex = cum - s;
#pragma unroll
  for (int rr = 0; rr < 2; rr++){
    int rank = 32768 + rr;
    if (basex < rank && cum >= rank){
      int c = basex;
      for (int u = 0; u < 32; u++){
        c += ghist[base + u];
        if (c >= rank){ bres[rr] = base + u; break; }
      }
    }
  }
  __syncthreads();
  if (t == 0){
    float med = 0.5f * ((bres[0] + 0.5f) + (bres[1] + 0.5f)) * (1.0f / 2048.0f);
    float bw = sqrtf(med * 0.5f);
    bw = fminf(fmaxf(bw, 0.1f), 10.0f);
    scal[3] = bw * bw;
  }
}

// ---------------- score reduction + last-block finalize ----------------
__global__ __launch_bounds__(256) void k_score(
    const float* __restrict__ z, const float* __restrict__ score,
    const float* __restrict__ dist, const float* __restrict__ ysy,
    float* __restrict__ scal, float* __restrict__ out)
{
  __shared__ __align__(16) float xsh[Kk];
  __shared__ __align__(16) float sxsh[Kk];
  __shared__ float red4[4];
  const int i = blockIdx.x, j = threadIdx.x;
  xsh[j]  = z[(size_t)i * Kk + j];
  sxsh[j] = score[(size_t)i * Kk + j];
  __syncthreads();
  const float bw2 = scal[3];
  const float4* sy4 = reinterpret_cast<const float4*>(score + (size_t)Bb * Kk);
  const float4* x4  = reinterpret_cast<const float4*>(xsh);
  const float4* sx4 = reinterpret_cast<const float4*>(sxsh);
  float ssy = 0, xsy = 0;
#pragma unroll 4
  for (int d = 0; d < Kk; d += 4){
    float4 xv  = x4[d >> 2];
    float4 sxv = sx4[d >> 2];
    float4 syv = sy4[j * (Kk/4) + (d >> 2)];
    ssy += sxv.x*syv.x + sxv.y*syv.y + sxv.z*syv.z + sxv.w*syv.w;
    xsy += xv.x*syv.x + xv.y*syv.y + xv.z*syv.z + xv.w*syv.w;
  }
  float d2 = dist[i * 256 + j];
  float kv = expf(-d2 / (2.0f * bw2));
  float t1 = kv * ssy;
  float t2 = (xsy - ysy[Bb + j]) * kv / bw2;
  float t3 = d2 * kv / (bw2 * bw2) - kv * (float)Kk / bw2;
  float s = wred(t1 + t2 + t3);
  if (!(j & 63)) red4[j >> 6] = s;
  __syncthreads();
  if (j == 0){
    atomicAdd(scal + 2, red4[0] + red4[1] + red4[2] + red4[3]);
    __threadfence();
    int old = atomicAdd(reinterpret_cast<int*>(scal + 4), 1);
    if (old == 255){
      float kli = __int_as_float(atomicAdd(reinterpret_cast<int*>(scal + 0), 0));
      float klt = __int_as_float(atomicAdd(reinterpret_cast<int*>(scal + 1), 0));
      float alg = __int_as_float(atomicAdd(reinterpret_cast<int*>(scal + 2), 0));
      out[0] = 0.5f * (kli + klt) * (1.0f/256.0f) + 0.1f * alg * (1.0f/65536.0f);
    }
  }
}

extern "C" void kernel_launch(void* const* d_in, const int* in_sizes, int n_in,
                              void* d_out, int out_size, void* d_ws, size_t ws_size,
                              hipStream_t stream) {
  (void)in_sizes; (void)n_in; (void)out_size; (void)ws_size;
  const float* img  = (const float*)d_in[0];
  const float* txt  = (const float*)d_in[1];
  const float* epsi = (const float*)d_in[2];
  const float* epst = (const float*)d_in[3];
  const int*   mask = (const int*)d_in[4];
  const float* eW1i = (const float*)d_in[5];
  const float* eb1i = (const float*)d_in[6];
  const float* egi  = (const float*)d_in[7];
  const float* ebei = (const float*)d_in[8];
  const float* eW2i = (const float*)d_in[9];
  const float* eb2i = (const float*)d_in[10];
  const float* eW1t = (const float*)d_in[11];
  const float* eb1t = (const float*)d_in[12];
  const float* egt  = (const float*)d_in[13];
  const float* ebet = (const float*)d_in[14];
  const float* eW2t = (const float*)d_in[15];
  const float* eb2t = (const float*)d_in[16];
  const float* sW1i = (const float*)d_in[17];
  const float* sb1i = (const float*)d_in[18];
  const float* sgi  = (const float*)d_in[19];
  const float* sbei = (const float*)d_in[20];
  const float* sW2i = (const float*)d_in[21];
  const float* sb2i = (const float*)d_in[22];
  const float* sW1t = (const float*)d_in[23];
  const float* sb1t = (const float*)d_in[24];
  const float* sgt  = (const float*)d_in[25];
  const float* sbet = (const float*)d_in[26];
  const float* sW2t = (const float*)d_in[27];
  const float* sb2t = (const float*)d_in[28];

  float*  ws    = (float*)d_ws;
  float*  epsg  = ws + OFF_EPSG;
  float*  P     = ws + OFF_P;
  float*  z     = ws + OFF_Z;
  float*  score = ws + OFF_SCORE;
  float*  dist  = ws + OFF_DIST;
  int*    ghist = (int*)(ws + OFF_HIST);
  float*  scal  = ws + OFF_SCAL;
  float*  ysy   = ws + OFF_YSY;
  ushort* ub    = (ushort*)(ws + OFF_BF);
  ushort* xgb   = ub + UB_XG;
  ushort* hb    = ub + UB_HACT;
  ushort* zb    = ub + UB_ZB;
  ushort* wt    = ub + UB_WT;

  // 1: prep (zero, seql, gather, weight conv)
  k_prep<<<3328, 256, 0, stream>>>(img, txt, epsi, epst, mask,
                                   eW1i, eW1t, eW2i, eW2t,
                                   sW1i, sW1t, sW2i, sW2t,
                                   xgb, epsg, wt, ghist, scal);
  // 2: enc GEMM1 [512,768]@[768,1024], ks=8 (512 blocks)
  k_mgemm<128,96,1024,768><<<dim3(16,4,8), 256, 0, stream>>>(xgb, wt+WT_EW1I, wt+WT_EW1T, P);
  // 3: LN1 (8 partials)
  k_ln1<8><<<512, 256, 0, stream>>>(P, eb1i, eb1t, egi, egt, ebei, ebet, hb);
  // 4: enc GEMM2 [512,1024]@[1024,512], ks=16 (512 blocks)
  k_mgemm<128,64,512,1024><<<dim3(8,4,16), 256, 0, stream>>>(hb, wt+WT_EW2I, wt+WT_EW2T, P);
  // 5: reparam (16 partials)
  k_reparam<16><<<512, 64, 0, stream>>>(P, eb2i, eb2t, epsg, z, zb, scal);
  // 6: sc GEMM1 (256 blocks) + dist/hist (256 blocks)
  k_sc1dist<<<512, 256, 0, stream>>>(zb, wt+WT_SW1I, wt+WT_SW1T, P, z, dist, ghist);
  // 7: LN2 (4 partials)
  k_ln2<4><<<512, 128, 0, stream>>>(P, sb1i, sb1t, sgi, sgt, sbei, sbet, hb);
  // 8: sc GEMM2 [512,512]@[512,256], ks=16 (512 blocks)
  k_mgemm<64,32,256,512><<<dim3(4,8,16), 256, 0, stream>>>(hb, wt+WT_SW2I, wt+WT_SW2T, P);
  // 9: score sum (128 blocks) + bw (1 block)
  k_sum2bw<16><<<129, 256, 0, stream>>>(P, sb2i, sb2t, z, score, ysy, ghist, scal);
  // 10: score reduction + finalize
  k_score<<<256, 256, 0, stream>>>(z, score, dist, ysy, scal, (float*)d_out);
}